// Round 6
// baseline (643.215 us; speedup 1.0000x reference)
//
#include <hip/hip_runtime.h>
#include <hip/hip_bf16.h>
#include <cstdint>
#include <cstddef>

#define NN   50000
#define EE   800000
#define ET_  (EE + NN)      // 850000 edges incl. self-loops
#define FIN  500
#define HID_ 160
#define NC_  20
#define GG   8
#define GB1  ((NN + 63) / 64)   // 782 GEMM blocks (64 rows each)
#define NK1  16                 // layer-1 k-steps (K=500 padded to 512)
#define NK2  5                  // K=160 k-steps

typedef __attribute__((ext_vector_type(8))) short ab8;   // 8 bf16 (4 VGPRs)
typedef __attribute__((ext_vector_type(4))) float f4;    // MFMA accumulator

static __device__ __forceinline__ unsigned short f2bf(float v) {
    union { float f; uint32_t u; } c; c.f = v;
    uint32_t r = c.u + 0x7FFFu + ((c.u >> 16) & 1u);  // RNE
    return (unsigned short)(r >> 16);
}

static __device__ __forceinline__ float2 bf2f2(uint32_t u) {
    // u holds bf16 pair (lo = even ch, hi = odd ch)
    union { uint32_t u; float f; } a, b;
    a.u = u << 16;
    b.u = u & 0xffff0000u;
    return make_float2(a.f, b.f);
}

static __device__ __forceinline__ int lbound_i(const int* arr, int n, int val) {
    int lo = 0, hi = n;
    while (lo < hi) { int mid = (lo + hi) >> 1; if (arr[mid] < val) lo = mid + 1; else hi = mid; }
    return lo;
}

// ---------------- CSR build ----------------
__global__ __launch_bounds__(256) void k_hist(const int* __restrict__ ei, int* __restrict__ deg) {
    int e = blockIdx.x * 256 + threadIdx.x;
    if (e >= ET_) return;
    int d = (e < EE) ? ei[EE + e] : (e - EE);
    atomicAdd(&deg[d], 1);
}

__global__ __launch_bounds__(256) void k_scan1(const int* __restrict__ deg, int* __restrict__ rowptr,
                                               int* __restrict__ bsum) {
    __shared__ int s[256];
    int t = threadIdx.x;
    int base = blockIdx.x * 1024 + t * 4;
    int v0 = (base + 0 < NN) ? deg[base + 0] : 0;
    int v1 = (base + 1 < NN) ? deg[base + 1] : 0;
    int v2 = (base + 2 < NN) ? deg[base + 2] : 0;
    int v3 = (base + 3 < NN) ? deg[base + 3] : 0;
    int tot = v0 + v1 + v2 + v3;
    s[t] = tot;
    __syncthreads();
    for (int off = 1; off < 256; off <<= 1) {
        int y = (t >= off) ? s[t - off] : 0;
        __syncthreads();
        s[t] += y;
        __syncthreads();
    }
    int excl = s[t] - tot;
    if (t == 255) bsum[blockIdx.x] = s[255];
    if (base + 0 < NN) rowptr[base + 0] = excl;  excl += v0;
    if (base + 1 < NN) rowptr[base + 1] = excl;  excl += v1;
    if (base + 2 < NN) rowptr[base + 2] = excl;  excl += v2;
    if (base + 3 < NN) rowptr[base + 3] = excl;
}

__global__ void k_scan2(int* __restrict__ bsum, int nb) {
    int t = threadIdx.x; // single wave of 64; nb <= 64
    int v = (t < nb) ? bsum[t] : 0;
    int orig = v;
    for (int off = 1; off < 64; off <<= 1) {
        int y = __shfl_up(v, off);
        if (t >= off) v += y;
    }
    if (t < nb) bsum[t] = v - orig; // exclusive prefix
}

__global__ __launch_bounds__(256) void k_scan3(int* __restrict__ rowptr, const int* __restrict__ bsum,
                                               int* __restrict__ cursor) {
    int i = blockIdx.x * 256 + threadIdx.x;
    if (i < NN) {
        int r = rowptr[i] + bsum[i >> 10];
        rowptr[i] = r;
        cursor[i] = r;
    }
    if (i == NN) rowptr[NN] = ET_;
}

// slot payload is just the src node (edge id not needed: alpha is emitted by the
// edge-ordered k_alpha kernel).
__global__ __launch_bounds__(256) void k_scatter(const int* __restrict__ ei, int* __restrict__ cursor,
                                                 int* __restrict__ esrc) {
    int e = blockIdx.x * 256 + threadIdx.x;
    if (e >= ET_) return;
    int s, d;
    if (e < EE) { s = ei[e]; d = ei[EE + e]; } else { s = e - EE; d = e - EE; }
    int slot = atomicAdd(&cursor[d], 1);
    esrc[slot] = s;
}

// ---------------- weight prep: fragment-packed B for all three GEMMs ----------------
// Bpk chunk (s,t,l): the 16B ab8 that lane l feeds MFMA t at k-step s.
// chunk value = W^T[n = t*16 + (l&15)][k0 = s*32 + (l>>4)*8 .. +8], zero-padded past K.
__global__ __launch_bounds__(256) void k_prep_all(const float* __restrict__ W1, ab8* __restrict__ B1,
                                                  const float* __restrict__ W2, ab8* __restrict__ B2,
                                                  const float* __restrict__ Wm, ab8* __restrict__ Bm,
                                                  float* __restrict__ pooled) {
    int idx = blockIdx.x * 256 + threadIdx.x;
    if (idx < GG * HID_) pooled[idx] = 0.f;
    const int C1 = NK1 * 10 * 64;      // 10240 chunks
    const int C2 = NK2 * 10 * 64;      // 3200 chunks
    const float* W; ab8* Bo; int K, cidx;
    if (idx < C1)                { W = W1; Bo = B1; K = FIN;  cidx = idx; }
    else if (idx < C1 + C2)      { W = W2; Bo = B2; K = HID_; cidx = idx - C1; }
    else if (idx < C1 + 2 * C2)  { W = Wm; Bo = Bm; K = HID_; cidx = idx - C1 - C2; }
    else return;
    int s = cidx / 640, r = cidx % 640;
    int t = r >> 6, l = r & 63;
    int fr = l & 15, q = l >> 4;
    int n  = t * 16 + fr;
    int k0 = s * 32 + q * 8;
    unsigned short pk[8];
#pragma unroll
    for (int j = 0; j < 8; j++) {
        int k = k0 + j;
        pk[j] = (k < K) ? f2bf(W[(size_t)k * HID_ + n]) : (unsigned short)0;
    }
    Bo[cidx] = *reinterpret_cast<ab8*>(pk);
}

// ---------------- x fp32 -> fragment-packed bf16 A for layer 1 ----------------
// Apk chunk ((blk*NK1 + s)*256 + tid): the ab8 that thread tid of GEMM block blk
// feeds its MFMA at k-step s. NOTE: Apk lives in the first 51.25MB of d_out
// (dead until later kernels).
__global__ __launch_bounds__(256) void k_conv_x(const float* __restrict__ x, ab8* __restrict__ Apk) {
    int idx = blockIdx.x * 256 + threadIdx.x;   // grid is exactly GB1*NK1*256 chunks
    int tid = idx & 255;
    int s   = (idx >> 8) & (NK1 - 1);
    int blk = idx >> 12;                         // NK1*256 = 4096
    int l = tid & 63, w = tid >> 6;
    int fr = l & 15, q = l >> 4;
    int row = blk * 64 + w * 16 + fr;
    int k0 = s * 32 + q * 8;
    unsigned short pk[8] = {0, 0, 0, 0, 0, 0, 0, 0};
    if (row < NN) {
        const float* xr = &x[(size_t)row * FIN];
        if (k0 + 8 <= FIN) {
            const float4* s4 = reinterpret_cast<const float4*>(&xr[k0]);
            float4 u = s4[0], v = s4[1];
            pk[0] = f2bf(u.x); pk[1] = f2bf(u.y); pk[2] = f2bf(u.z); pk[3] = f2bf(u.w);
            pk[4] = f2bf(v.x); pk[5] = f2bf(v.y); pk[6] = f2bf(v.z); pk[7] = f2bf(v.w);
        } else {
#pragma unroll
            for (int j = 0; j < 8; j++)
                if (k0 + j < FIN) pk[j] = f2bf(xr[k0 + j]);
        }
    }
    Apk[idx] = *reinterpret_cast<ab8*>(pk);
}

// ---------------- register-resident MFMA GEMM: C[M,160] = A[M,K] @ W[K,160] ----------------
// NO LDS, NO barriers, NO scattered loads. A is ALWAYS fragment-packed
// (layer 1: k_conv_x; layers 2/3: k_att_agg emits packed directly) — every A
// load is a contiguous 4KB block-burst, every B load a 1KB wave burst.
// Fused epilogues:
//  - asrc/adst -> als/ald: per-row per-head attention dots (GAT layers)
//  - batch+pooled: global mean-pool partial sums (readout GEMM)
static __device__ __forceinline__ void gemm_body(const ab8* __restrict__ Apk,
                                                 const ab8* __restrict__ Bpk, int nk,
                                                 float* __restrict__ C, __hip_bfloat16* __restrict__ Cb,
                                                 int M,
                                                 const float* __restrict__ bias, int act,
                                                 const float* __restrict__ asrc, const float* __restrict__ adst,
                                                 float* __restrict__ als_o, float* __restrict__ ald_o,
                                                 const int* __restrict__ batch_p, float* __restrict__ pooled) {
    int tid  = threadIdx.x;
    int lane = tid & 63;
    int w    = tid >> 6;
    int fr   = lane & 15;        // fragment row/col index
    int q    = lane >> 4;        // quad: k-subtile for inputs, row-subtile for output
    int row0 = blockIdx.x * 64;

    f4 acc[10];
#pragma unroll
    for (int t = 0; t < 10; t++) acc[t] = (f4)0.f;

    const ab8* bb  = Bpk + lane;
    const ab8* apk = Apk + (size_t)blockIdx.x * nk * 256 + tid;

    ab8 bcur[10], bnx[10];
#pragma unroll
    for (int t = 0; t < 10; t++) bcur[t] = bb[t * 64];
    ab8 a0 = apk[0];
    ab8 a1 = apk[256];               // nk >= 5 always
    for (int s = 0; s < nk; s++) {
        if (s + 1 < nk) {
#pragma unroll
            for (int t = 0; t < 10; t++) bnx[t] = bb[((s + 1) * 10 + t) * 64];
        }
        ab8 a2 = (ab8)0;
        if (s + 2 < nk) a2 = apk[(s + 2) * 256];
#pragma unroll
        for (int t = 0; t < 10; t++)
            acc[t] = __builtin_amdgcn_mfma_f32_16x16x32_bf16(a0, bcur[t], acc[t], 0, 0, 0);
        a0 = a1; a1 = a2;
#pragma unroll
        for (int t = 0; t < 10; t++) bcur[t] = bnx[t];
    }

    // ---- fused per-node attention dots: als/ald (GAT layers), stride-8 rows ----
    if (als_o) {
        float av_s[10], av_d[10];
#pragma unroll
        for (int t = 0; t < 10; t++) { av_s[t] = asrc[t * 16 + fr]; av_d[t] = adst[t * 16 + fr]; }
#pragma unroll
        for (int i = 0; i < 4; i++) {
            int r = row0 + w * 16 + q * 4 + i;
            float ps[5], pd[5];
#pragma unroll
            for (int h = 0; h < 5; h++) {
                ps[h] = acc[2 * h][i] * av_s[2 * h] + acc[2 * h + 1][i] * av_s[2 * h + 1];
                pd[h] = acc[2 * h][i] * av_d[2 * h] + acc[2 * h + 1][i] * av_d[2 * h + 1];
            }
#pragma unroll
            for (int off = 8; off >= 1; off >>= 1)
#pragma unroll
                for (int h = 0; h < 5; h++) {
                    ps[h] += __shfl_xor(ps[h], off);
                    pd[h] += __shfl_xor(pd[h], off);
                }
            if (fr == 0 && r < M) {
#pragma unroll
                for (int h = 0; h < 5; h++) {
                    als_o[(size_t)r * 8 + h] = ps[h];
                    ald_o[(size_t)r * 8 + h] = pd[h];
                }
            }
        }
    }

    // ---- pool setup (readout GEMM): block-uniform-graph fast path ----
    int gu = -2;
    if (pooled) {
        int rhi = row0 + 63; if (rhi >= M) rhi = M - 1;
        int gl = batch_p[row0], gh = batch_p[rhi];
        gu = (gl == gh) ? gl : -1;
    }
    float psum[10];
#pragma unroll
    for (int t = 0; t < 10; t++) psum[t] = 0.f;

    // ---- epilogue: C/D layout col=lane&15, row=(lane>>4)*4+reg ----
    int rbase = row0 + w * 16 + q * 4;
#pragma unroll
    for (int t = 0; t < 10; t++) {
        int col = t * 16 + fr;
        float bv = bias ? bias[col] : 0.f;
#pragma unroll
        for (int i = 0; i < 4; i++) {
            int r = rbase + i;
            float v = acc[t][i] + bv;
            if (act) v = v > 0.f ? v : 0.01f * v;
            if (r < M) {
                if (C)  C[(size_t)r * HID_ + col] = v;
                if (Cb) *reinterpret_cast<unsigned short*>(&Cb[(size_t)r * HID_ + col]) = f2bf(v);
                if (gu >= 0) psum[t] += v;
                else if (gu == -1) atomicAdd(&pooled[batch_p[r] * HID_ + col], v);
            }
        }
    }
    if (gu >= 0) {
#pragma unroll
        for (int t = 0; t < 10; t++) {
            psum[t] += __shfl_xor(psum[t], 16);
            psum[t] += __shfl_xor(psum[t], 32);
        }
        if (q == 0) {
#pragma unroll
            for (int t = 0; t < 10; t++)
                atomicAdd(&pooled[gu * HID_ + t * 16 + fr], psum[t]);
        }
    }
}

__global__ __launch_bounds__(256) void k_gemm_pk(const ab8* __restrict__ Apk,
                                                 const ab8* __restrict__ Bpk, int nk,
                                                 float* __restrict__ C, __hip_bfloat16* __restrict__ Cb,
                                                 int M,
                                                 const float* __restrict__ bias, int act,
                                                 const float* __restrict__ asrc, const float* __restrict__ adst,
                                                 float* __restrict__ als_o, float* __restrict__ ald_o,
                                                 const int* __restrict__ batch_p, float* __restrict__ pooled) {
    gemm_body(Apk, Bpk, nk, C, Cb, M, bias, act, asrc, adst, als_o, ald_o, batch_p, pooled);
}

// ---------- fused edge softmax + aggregation + bias + leaky + LayerNorm ----------
// One wave per destination node. Channel map: lane l owns ch {2l,2l+1}; lanes 0..15
// additionally own {128+2l,128+2l+1} (head 4). Aggregation is 4-edge unrolled with
// pre-normalized LDS weights. Output is emitted DIRECTLY in the GEMM's packed-A
// fragment layout (shuffles assemble 20x16B chunks; lanes 0..19 store) so the
// downstream K=160 GEMMs read fully-coalesced A.
__global__ __launch_bounds__(256) void k_att_agg(const int* __restrict__ rowptr,
                                                 const int* __restrict__ esrc,
                                                 const float* __restrict__ als, const float* __restrict__ ald,
                                                 const __hip_bfloat16* __restrict__ hmat,
                                                 float* __restrict__ alphap,      // [ET_*5] overflow scratch
                                                 float* __restrict__ invb,        // [NN*8] per-node 1/sum
                                                 const float* __restrict__ bias,
                                                 const float* __restrict__ lns, const float* __restrict__ lnb,
                                                 uint4* __restrict__ xpk) {       // packed-A output
    __shared__ float sExp[4][64 * 5];
    __shared__ int   sSrc[4][64];
    int wv   = threadIdx.x >> 6;
    int lane = threadIdx.x & 63;
    int node = blockIdx.x * 4 + wv;
    if (node >= NN) return;
    int start = rowptr[node], end = rowptr[node + 1];
    int deg = end - start;
    bool fits = (deg <= 64);
    float4 dd4 = *reinterpret_cast<const float4*>(&ald[(size_t)node * 8]);
    float  dd5 = ald[(size_t)node * 8 + 4];
    float ad[5] = {dd4.x, dd4.y, dd4.z, dd4.w, dd5};

    // ---- pass 1: exp(leaky(logit)), lane-parallel over edges ----
    float sm[5] = {0.f, 0.f, 0.f, 0.f, 0.f};
    for (int j = start + lane; j < end; j += 64) {
        int sy = esrc[j];
        int idx = j - start;
        if (fits) sSrc[wv][idx] = sy;
        const float* as = &als[(size_t)sy * 8];
        float4 a4 = *reinterpret_cast<const float4*>(as);
        float  a5 = as[4];
        float asv[5] = {a4.x, a4.y, a4.z, a4.w, a5};
#pragma unroll
        for (int h = 0; h < 5; h++) {
            float l = asv[h] + ad[h];
            l = l > 0.f ? l : 0.2f * l;
            float ex = __expf(fminf(l, 60.f));
            sm[h] += ex;
            if (fits) sExp[wv][idx * 5 + h] = ex;
            else      alphap[(size_t)j * 5 + h] = ex;
        }
    }
#pragma unroll
    for (int off = 32; off >= 1; off >>= 1)
#pragma unroll
        for (int h = 0; h < 5; h++) sm[h] += __shfl_xor(sm[h], off);
    float inv[5];
#pragma unroll
    for (int h = 0; h < 5; h++) inv[h] = 1.f / (sm[h] + 1e-16f);
    if (lane == 0) {
        float* ip = &invb[(size_t)node * 8];
        ip[0] = inv[0]; ip[1] = inv[1]; ip[2] = inv[2]; ip[3] = inv[3]; ip[4] = inv[4];
    }
    // pre-normalize LDS weights (same product as per-use multiply -> bit-identical)
    if (fits && lane < deg) {
#pragma unroll
        for (int h = 0; h < 5; h++) sExp[wv][lane * 5 + h] *= inv[h];
    }

    int h0 = lane >> 4;            // head of ch pair (2l,2l+1): 0..3
    bool lo16 = lane < 16;         // lanes 0..15 own head-4 pair {128+2l,128+2l+1}
    int c01 = 2 * lane;            // first ch pair
    int c2  = 128 + 2 * lane;      // second ch pair (lo16 only; 128..158)
    float2 A0 = make_float2(0.f, 0.f), A1 = make_float2(0.f, 0.f);
    float2 A2 = make_float2(0.f, 0.f), A3 = make_float2(0.f, 0.f);
    float2 H0 = make_float2(0.f, 0.f), H1 = make_float2(0.f, 0.f);
    float2 H2 = make_float2(0.f, 0.f), H3 = make_float2(0.f, 0.f);

    if (fits) {
        // ---- aggregation: 4-edge unrolled, ch pairs across lanes ----
        int idx = 0;
        for (; idx + 3 < deg; idx += 4) {
            int s0 = sSrc[wv][idx], s1 = sSrc[wv][idx + 1];
            int s2 = sSrc[wv][idx + 2], s3 = sSrc[wv][idx + 3];
            float w0 = sExp[wv][(idx + 0) * 5 + h0];
            float w1 = sExp[wv][(idx + 1) * 5 + h0];
            float w2 = sExp[wv][(idx + 2) * 5 + h0];
            float w3 = sExp[wv][(idx + 3) * 5 + h0];
            const unsigned short* r0 = (const unsigned short*)&hmat[(size_t)s0 * HID_];
            const unsigned short* r1 = (const unsigned short*)&hmat[(size_t)s1 * HID_];
            const unsigned short* r2 = (const unsigned short*)&hmat[(size_t)s2 * HID_];
            const unsigned short* r3 = (const unsigned short*)&hmat[(size_t)s3 * HID_];
            float2 f0 = bf2f2(*reinterpret_cast<const uint32_t*>(&r0[c01]));
            float2 f1 = bf2f2(*reinterpret_cast<const uint32_t*>(&r1[c01]));
            float2 f2 = bf2f2(*reinterpret_cast<const uint32_t*>(&r2[c01]));
            float2 f3 = bf2f2(*reinterpret_cast<const uint32_t*>(&r3[c01]));
            A0.x += w0 * f0.x; A0.y += w0 * f0.y;
            A1.x += w1 * f1.x; A1.y += w1 * f1.y;
            A2.x += w2 * f2.x; A2.y += w2 * f2.y;
            A3.x += w3 * f3.x; A3.y += w3 * f3.y;
            if (lo16) {
                float u0 = sExp[wv][(idx + 0) * 5 + 4];
                float u1 = sExp[wv][(idx + 1) * 5 + 4];
                float u2 = sExp[wv][(idx + 2) * 5 + 4];
                float u3 = sExp[wv][(idx + 3) * 5 + 4];
                float2 g0 = bf2f2(*reinterpret_cast<const uint32_t*>(&r0[c2]));
                float2 g1 = bf2f2(*reinterpret_cast<const uint32_t*>(&r1[c2]));
                float2 g2 = bf2f2(*reinterpret_cast<const uint32_t*>(&r2[c2]));
                float2 g3 = bf2f2(*reinterpret_cast<const uint32_t*>(&r3[c2]));
                H0.x += u0 * g0.x; H0.y += u0 * g0.y;
                H1.x += u1 * g1.x; H1.y += u1 * g1.y;
                H2.x += u2 * g2.x; H2.y += u2 * g2.y;
                H3.x += u3 * g3.x; H3.y += u3 * g3.y;
            }
        }
        for (; idx < deg; idx++) {
            int s0 = sSrc[wv][idx];
            float w0 = sExp[wv][idx * 5 + h0];
            const unsigned short* r0 = (const unsigned short*)&hmat[(size_t)s0 * HID_];
            float2 f0 = bf2f2(*reinterpret_cast<const uint32_t*>(&r0[c01]));
            A0.x += w0 * f0.x; A0.y += w0 * f0.y;
            if (lo16) {
                float u0 = sExp[wv][idx * 5 + 4];
                float2 g0 = bf2f2(*reinterpret_cast<const uint32_t*>(&r0[c2]));
                H0.x += u0 * g0.x; H0.y += u0 * g0.y;
            }
        }
    } else {
        // ---- overflow path (deg > 64): exp staged in global scratch ----
        for (int j = start; j < end; j++) {
            int s0 = esrc[j];
            float w0 = alphap[(size_t)j * 5 + h0] * inv[h0];
            const unsigned short* r0 = (const unsigned short*)&hmat[(size_t)s0 * HID_];
            float2 f0 = bf2f2(*reinterpret_cast<const uint32_t*>(&r0[c01]));
            A0.x += w0 * f0.x; A0.y += w0 * f0.y;
            if (lo16) {
                float u0 = alphap[(size_t)j * 5 + 4] * inv[4];
                float2 g0 = bf2f2(*reinterpret_cast<const uint32_t*>(&r0[c2]));
                H0.x += u0 * g0.x; H0.y += u0 * g0.y;
            }
        }
    }
    float2 A = make_float2(A0.x + A1.x + A2.x + A3.x, A0.y + A1.y + A2.y + A3.y);
    float2 Hh = make_float2(H0.x + H1.x + H2.x + H3.x, H0.y + H1.y + H2.y + H3.y);

    // ---- bias + leaky(0.01) + LayerNorm ----
    float2 bb = *reinterpret_cast<const float2*>(&bias[c01]);
    float v0 = A.x + bb.x;  v0 = v0 > 0.f ? v0 : 0.01f * v0;
    float v1 = A.y + bb.y;  v1 = v1 > 0.f ? v1 : 0.01f * v1;
    float v2 = 0.f, v3 = 0.f;
    if (lo16) {
        float2 b2 = *reinterpret_cast<const float2*>(&bias[c2]);
        v2 = Hh.x + b2.x; v2 = v2 > 0.f ? v2 : 0.01f * v2;
        v3 = Hh.y + b2.y; v3 = v3 > 0.f ? v3 : 0.01f * v3;
    }
    float s  = v0 + v1 + v2 + v3;
    float sq = v0 * v0 + v1 * v1 + v2 * v2 + v3 * v3;
#pragma unroll
    for (int off = 32; off >= 1; off >>= 1) {
        s  += __shfl_xor(s, off);
        sq += __shfl_xor(sq, off);
    }
    float m = s * (1.f / 160.f);
    float r = rsqrtf(sq * (1.f / 160.f) - m * m + 1e-5f);
    uint32_t pk1, pk2 = 0u;
    {
        float2 sc = *reinterpret_cast<const float2*>(&lns[c01]);
        float2 bi = *reinterpret_cast<const float2*>(&lnb[c01]);
        pk1 = (uint32_t)f2bf((v0 - m) * r * sc.x + bi.x)
            | ((uint32_t)f2bf((v1 - m) * r * sc.y + bi.y) << 16);
    }
    if (lo16) {
        float2 sc = *reinterpret_cast<const float2*>(&lns[c2]);
        float2 bi = *reinterpret_cast<const float2*>(&lnb[c2]);
        pk2 = (uint32_t)f2bf((v2 - m) * r * sc.x + bi.x)
            | ((uint32_t)f2bf((v3 - m) * r * sc.y + bi.y) << 16);
    }
    // ---- repack node row into GEMM fragment chunks (20 x 16B) ----
    // chunk j covers ch 8j..8j+7 = pairs 4j..4j+3 (pk1 of lanes 4j.. if j<16,
    // else pk2 of lanes 4(j-16)..). srcb clamped to [0,60] so every __shfl lane
    // index is in range for all 64 lanes (results discarded for j>=20).
    int j = lane;
    int srcb = (j < 16) ? (4 * j) : (4 * ((j - 16) & 15));
    uint32_t a0w = __shfl(pk1, srcb + 0), a1w = __shfl(pk1, srcb + 1);
    uint32_t a2w = __shfl(pk1, srcb + 2), a3w = __shfl(pk1, srcb + 3);
    uint32_t b0w = __shfl(pk2, srcb + 0), b1w = __shfl(pk2, srcb + 1);
    uint32_t b2w = __shfl(pk2, srcb + 2), b3w = __shfl(pk2, srcb + 3);
    if (j < 20) {
        uint4 val;
        val.x = (j < 16) ? a0w : b0w;
        val.y = (j < 16) ? a1w : b1w;
        val.z = (j < 16) ? a2w : b2w;
        val.w = (j < 16) ? a3w : b3w;
        int blk = node >> 6, wq = (node >> 4) & 3, fr = node & 15;
        int ks = j >> 2, q = j & 3;
        size_t cidx = (size_t)(blk * NK2 + ks) * 256 + wq * 64 + q * 16 + fr;
        xpk[cidx] = val;
    }
}

// ---------- edge-ordered alpha emission: fully coalesced 20B/edge writes ----------
__global__ __launch_bounds__(256) void k_alpha(const int* __restrict__ ei,
                                               const float* __restrict__ als, const float* __restrict__ ald,
                                               const float* __restrict__ invb,
                                               float* __restrict__ alpha_out) {
    int e = blockIdx.x * 256 + threadIdx.x;
    if (e >= ET_) return;
    int s, d;
    if (e < EE) { s = ei[e]; d = ei[EE + e]; } else { s = e - EE; d = e - EE; }
    const float* as = &als[(size_t)s * 8];
    float4 a4 = *reinterpret_cast<const float4*>(as);
    float  a5 = as[4];
    float asv[5] = {a4.x, a4.y, a4.z, a4.w, a5};
    const float* adp = &ald[(size_t)d * 8];
    float4 d4 = *reinterpret_cast<const float4*>(adp);
    float  d5 = adp[4];
    float adv[5] = {d4.x, d4.y, d4.z, d4.w, d5};
    const float* ip = &invb[(size_t)d * 8];
    float4 i4 = *reinterpret_cast<const float4*>(ip);
    float  i5 = ip[4];
    float ivv[5] = {i4.x, i4.y, i4.z, i4.w, i5};
    float* ao = &alpha_out[(size_t)e * 5];
#pragma unroll
    for (int h = 0; h < 5; h++) {
        float l = asv[h] + adv[h];
        l = l > 0.f ? l : 0.2f * l;
        float ex = __expf(fminf(l, 60.f));
        ao[h] = ex * ivv[h];
    }
}

// ---------------- readout MLP (single block) ----------------
__global__ __launch_bounds__(256) void k_mlp(const float* __restrict__ pooled, const int* __restrict__ batch,
                                             const float* __restrict__ W1, const float* __restrict__ b1,
                                             const float* __restrict__ lns, const float* __restrict__ lnb,
                                             const float* __restrict__ W2, const float* __restrict__ b2,
                                             float* __restrict__ rec) {
    __shared__ float P[GG][HID_];
    __shared__ float Z[GG][HID_];
    __shared__ float mu[GG], rr[GG], ic[GG];
    int t = threadIdx.x;
    if (t < GG) {
        int lo = lbound_i(batch, NN, t), hi = lbound_i(batch, NN, t + 1);
        ic[t] = 1.f / fmaxf((float)(hi - lo), 1.f);
    }
    __syncthreads();
    for (int i = t; i < GG * HID_; i += 256) P[i / HID_][i % HID_] = pooled[i] * ic[i / HID_];
    __syncthreads();
    for (int i = t; i < GG * HID_; i += 256) {
        int g = i / HID_, j = i % HID_;
        float acc = b1[j];
        for (int k = 0; k < HID_; k++) acc += P[g][k] * W1[k * HID_ + j];
        Z[g][j] = acc;
    }
    __syncthreads();
    if (t < GG) {
        float s = 0.f, sq = 0.f;
        for (int k = 0; k < HID_; k++) { float z = Z[t][k]; s += z; sq += z * z; }
        float m = s / (float)HID_;
        mu[t] = m;
        rr[t] = rsqrtf(sq / (float)HID_ - m * m + 1e-5f);
    }
    __syncthreads();
    for (int i = t; i < GG * HID_; i += 256) {
        int g = i / HID_, j = i % HID_;
        float z = (Z[g][j] - mu[g]) * rr[g] * lns[j] + lnb[j];
        Z[g][j] = fmaxf(z, 0.f);
    }
    __syncthreads();
    for (int i = t; i < GG * NC_; i += 256) {
        int g = i / NC_, j = i % NC_;
        float acc = b2[j];
        for (int k = 0; k < HID_; k++) acc += Z[g][k] * W2[k * NC_ + j];
        rec[g * NC_ + j] = acc;
    }
}

extern "C" void kernel_launch(void* const* d_in, const int* in_sizes, int n_in,
                              void* d_out, int out_size, void* d_ws, size_t ws_size,
                              hipStream_t stream) {
    const float* x    = (const float*)d_in[0];
    const int*   ei   = (const int*)d_in[1];
    const int*   batch= (const int*)d_in[2];
    const float* W1   = (const float*)d_in[3];
    const float* as1  = (const float*)d_in[4];
    const float* ad1  = (const float*)d_in[5];
    const float* b1   = (const float*)d_in[6];
    const float* ln1s = (const float*)d_in[7];
    const float* ln1b = (const float*)d_in[8];
    const float* W2   = (const float*)d_in[9];
    const float* as2  = (const float*)d_in[10];
    const float* ad2  = (const float*)d_in[11];
    const float* b2   = (const float*)d_in[12];
    const float* ln2s = (const float*)d_in[13];
    const float* ln2b = (const float*)d_in[14];
    const float* Wm   = (const float*)d_in[15];
    const float* bm   = (const float*)d_in[16];
    const float* Wm1  = (const float*)d_in[17];
    const float* bm1  = (const float*)d_in[18];
    const float* ln3s = (const float*)d_in[19];
    const float* ln3b = (const float*)d_in[20];
    const float* Wm2  = (const float*)d_in[21];
    const float* bm2  = (const float*)d_in[22];

    float* out    = (float*)d_out;
    float* xo     = out;                              // N*160
    float* rec    = out + (size_t)NN * HID_;          // 8*20
    float* alpha1 = rec + GG * NC_;                   // ET*5
    float* alpha2 = alpha1 + (size_t)ET_ * 5;         // ET*5

    char* w = (char*)d_ws;
    auto carve = [&](size_t bytes) { char* p = w; w += (bytes + 255) & ~(size_t)255; return p; };
    int*   deg    = (int*)carve((size_t)NN * 4);
    int*   rowptr = (int*)carve((size_t)(NN + 1) * 4);
    int*   cursor = (int*)carve((size_t)NN * 4);
    int*   esrc   = (int*)carve((size_t)ET_ * 4);
    int*   bsum   = (int*)carve(64 * 4);
    __hip_bfloat16* hbuf = (__hip_bfloat16*)carve((size_t)NN * HID_ * 2);
    uint4* xpk    = (uint4*)carve((size_t)GB1 * NK2 * 256 * 16);  // packed attn output (16MB)
    float* alphap = (float*)carve((size_t)ET_ * 5 * 4);
    float* als    = (float*)carve((size_t)NN * 8 * 4);
    float* ald    = (float*)carve((size_t)NN * 8 * 4);
    float* invb   = (float*)carve((size_t)NN * 8 * 4);
    float* pooled = (float*)carve((size_t)GG * HID_ * 4);
    ab8*   B1pk   = (ab8*)carve((size_t)NK1 * 10 * 64 * 16);     // 160 KB
    ab8*   B2pk   = (ab8*)carve((size_t)NK2 * 10 * 64 * 16);     // 50 KB
    ab8*   Bmpk   = (ab8*)carve((size_t)NK2 * 10 * 64 * 16);     // 50 KB
    // Apk (51.25MB) lives in d_out: dead until k_att_agg/readout, which all run
    // after the layer-1 GEMM finishes reading it.
    ab8*   Apk    = (ab8*)d_out;                                 // GB1*NK1*256*16 B

    // ---- CSR by destination (rebuilt every call; ws is re-poisoned) ----
    hipMemsetAsync(deg, 0, (size_t)NN * 4, stream);
    k_hist<<<(ET_ + 255) / 256, 256, 0, stream>>>(ei, deg);
    int nb = (NN + 1023) / 1024;
    k_scan1<<<nb, 256, 0, stream>>>(deg, rowptr, bsum);
    k_scan2<<<1, 64, 0, stream>>>(bsum, nb);
    k_scan3<<<(NN + 1 + 255) / 256, 256, 0, stream>>>(rowptr, bsum, cursor);
    k_scatter<<<(ET_ + 255) / 256, 256, 0, stream>>>(ei, cursor, esrc);

    // ---- weight prep (fragment-packed B; also zeroes pooled) + packed-A conversion ----
    const int PREP = NK1 * 10 * 64 + 2 * NK2 * 10 * 64;  // 16640 chunk threads
    k_prep_all<<<(PREP + 255) / 256, 256, 0, stream>>>(W1, B1pk, W2, B2pk, Wm, Bmpk, pooled);
    k_conv_x<<<GB1 * NK1, 256, 0, stream>>>(x, Apk);

    const int NWB = (NN + 3) / 4;         // wave-per-node blocks (4 waves/block)
    const int EB  = (ET_ + 255) / 256;    // edge-parallel blocks

    // ---- layer 1 ----
    k_gemm_pk<<<GB1, 256, 0, stream>>>(Apk, B1pk, NK1, nullptr, hbuf, NN, nullptr, 0,
                                       as1, ad1, als, ald, nullptr, nullptr);
    k_att_agg<<<NWB, 256, 0, stream>>>(rowptr, esrc, als, ald, hbuf, alphap, invb,
                                       b1, ln1s, ln1b, xpk);
    k_alpha<<<EB, 256, 0, stream>>>(ei, als, ald, invb, alpha1);

    // ---- layer 2 ----
    k_gemm_pk<<<GB1, 256, 0, stream>>>((const ab8*)xpk, B2pk, NK2, nullptr, hbuf, NN, nullptr, 0,
                                       as2, ad2, als, ald, nullptr, nullptr);
    k_att_agg<<<NWB, 256, 0, stream>>>(rowptr, esrc, als, ald, hbuf, alphap, invb,
                                       b2, ln2s, ln2b, xpk);
    k_alpha<<<EB, 256, 0, stream>>>(ei, als, ald, invb, alpha2);

    // ---- readout: GEMM + fused mean-pool partials ----
    k_gemm_pk<<<GB1, 256, 0, stream>>>((const ab8*)xpk, Bmpk, NK2, xo, nullptr, NN, bm, 1,
                                       nullptr, nullptr, nullptr, nullptr, batch, pooled);
    k_mlp<<<1, 256, 0, stream>>>(pooled, batch, Wm1, bm1, ln3s, ln3b, Wm2, bm2, rec);
}

// Round 7
// 612.243 us; speedup vs baseline: 1.0506x; 1.0506x over previous
//
#include <hip/hip_runtime.h>
#include <hip/hip_bf16.h>
#include <cstdint>
#include <cstddef>

#define NN   50000
#define EE   800000
#define ET_  (EE + NN)      // 850000 edges incl. self-loops
#define FIN  500
#define HID_ 160
#define NC_  20
#define GG   8
#define GB1  ((NN + 63) / 64)   // 782 GEMM blocks (64 rows each)
#define NK1  16                 // layer-1 k-steps (K=500 padded to 512)
#define NK2  5                  // K=160 k-steps
#define EBH  ((ET_ + 255) / 256) // 3321 edge-parallel blocks

typedef __attribute__((ext_vector_type(8))) short ab8;   // 8 bf16 (4 VGPRs)
typedef __attribute__((ext_vector_type(4))) float f4;    // MFMA accumulator

static __device__ __forceinline__ unsigned short f2bf(float v) {
    union { float f; uint32_t u; } c; c.f = v;
    uint32_t r = c.u + 0x7FFFu + ((c.u >> 16) & 1u);  // RNE
    return (unsigned short)(r >> 16);
}

static __device__ __forceinline__ float2 bf2f2(uint32_t u) {
    // u holds bf16 pair (lo = even ch, hi = odd ch)
    union { uint32_t u; float f; } a, b;
    a.u = u << 16;
    b.u = u & 0xffff0000u;
    return make_float2(a.f, b.f);
}

static __device__ __forceinline__ int lbound_i(const int* arr, int n, int val) {
    int lo = 0, hi = n;
    while (lo < hi) { int mid = (lo + hi) >> 1; if (arr[mid] < val) lo = mid + 1; else hi = mid; }
    return lo;
}

// ---------------- prep0: zero deg + pooled, pack B for all three GEMMs ----------------
// Bpk chunk (s,t,l): the 16B ab8 that lane l feeds MFMA t at k-step s.
// chunk value = W^T[n = t*16 + (l&15)][k0 = s*32 + (l>>4)*8 .. +8], zero-padded past K.
__global__ __launch_bounds__(256) void k_prep0(const float* __restrict__ W1, ab8* __restrict__ B1,
                                               const float* __restrict__ W2, ab8* __restrict__ B2,
                                               const float* __restrict__ Wm, ab8* __restrict__ Bm,
                                               float* __restrict__ pooled, int* __restrict__ deg) {
    int idx = blockIdx.x * 256 + threadIdx.x;      // grid covers NN threads
    if (idx < NN) deg[idx] = 0;
    if (idx < GG * HID_) pooled[idx] = 0.f;
    const int C1 = NK1 * 10 * 64;      // 10240 chunks
    const int C2 = NK2 * 10 * 64;      // 3200 chunks
    const float* W; ab8* Bo; int K, cidx;
    if (idx < C1)                { W = W1; Bo = B1; K = FIN;  cidx = idx; }
    else if (idx < C1 + C2)      { W = W2; Bo = B2; K = HID_; cidx = idx - C1; }
    else if (idx < C1 + 2 * C2)  { W = Wm; Bo = Bm; K = HID_; cidx = idx - C1 - C2; }
    else return;
    int s = cidx / 640, r = cidx % 640;
    int t = r >> 6, l = r & 63;
    int fr = l & 15, q = l >> 4;
    int n  = t * 16 + fr;
    int k0 = s * 32 + q * 8;
    unsigned short pk[8];
#pragma unroll
    for (int j = 0; j < 8; j++) {
        int k = k0 + j;
        pk[j] = (k < K) ? f2bf(W[(size_t)k * HID_ + n]) : (unsigned short)0;
    }
    Bo[cidx] = *reinterpret_cast<ab8*>(pk);
}

// ---------------- fused: edge histogram + x fp32 -> fragment-packed bf16 A ----------------
// Blocks [0,EBH): k_hist (atomic deg counts). Blocks [EBH, EBH+GB1*NK1): k_conv_x
// (fragment-packed layer-1 A, fully coalesced writes). Independent work co-scheduled
// so the atomic latency hides under the streaming conversion.
// Apk lives in the first 51.25MB of d_out (dead until later kernels).
__global__ __launch_bounds__(256) void k_hist_conv(const int* __restrict__ ei, int* __restrict__ deg,
                                                   const float* __restrict__ x, ab8* __restrict__ Apk) {
    if (blockIdx.x < EBH) {
        int e = blockIdx.x * 256 + threadIdx.x;
        if (e >= ET_) return;
        int d = (e < EE) ? ei[EE + e] : (e - EE);
        atomicAdd(&deg[d], 1);
        return;
    }
    int idx = (blockIdx.x - EBH) * 256 + threadIdx.x;
    int tid = idx & 255;
    int s   = (idx >> 8) & (NK1 - 1);
    int blk = idx >> 12;                         // NK1*256 = 4096
    int l = tid & 63, w = tid >> 6;
    int fr = l & 15, q = l >> 4;
    int row = blk * 64 + w * 16 + fr;
    int k0 = s * 32 + q * 8;
    unsigned short pk[8] = {0, 0, 0, 0, 0, 0, 0, 0};
    if (row < NN) {
        const float* xr = &x[(size_t)row * FIN];
        if (k0 + 8 <= FIN) {
            const float4* s4 = reinterpret_cast<const float4*>(&xr[k0]);
            float4 u = s4[0], v = s4[1];
            pk[0] = f2bf(u.x); pk[1] = f2bf(u.y); pk[2] = f2bf(u.z); pk[3] = f2bf(u.w);
            pk[4] = f2bf(v.x); pk[5] = f2bf(v.y); pk[6] = f2bf(v.z); pk[7] = f2bf(v.w);
        } else {
#pragma unroll
            for (int j = 0; j < 8; j++)
                if (k0 + j < FIN) pk[j] = f2bf(xr[k0 + j]);
        }
    }
    Apk[idx] = *reinterpret_cast<ab8*>(pk);
}

// ---------------- CSR scans ----------------
__global__ __launch_bounds__(256) void k_scan1(const int* __restrict__ deg, int* __restrict__ rowptr,
                                               int* __restrict__ bsum) {
    __shared__ int s[256];
    int t = threadIdx.x;
    int base = blockIdx.x * 1024 + t * 4;
    int v0 = (base + 0 < NN) ? deg[base + 0] : 0;
    int v1 = (base + 1 < NN) ? deg[base + 1] : 0;
    int v2 = (base + 2 < NN) ? deg[base + 2] : 0;
    int v3 = (base + 3 < NN) ? deg[base + 3] : 0;
    int tot = v0 + v1 + v2 + v3;
    s[t] = tot;
    __syncthreads();
    for (int off = 1; off < 256; off <<= 1) {
        int y = (t >= off) ? s[t - off] : 0;
        __syncthreads();
        s[t] += y;
        __syncthreads();
    }
    int excl = s[t] - tot;
    if (t == 255) bsum[blockIdx.x] = s[255];
    if (base + 0 < NN) rowptr[base + 0] = excl;  excl += v0;
    if (base + 1 < NN) rowptr[base + 1] = excl;  excl += v1;
    if (base + 2 < NN) rowptr[base + 2] = excl;  excl += v2;
    if (base + 3 < NN) rowptr[base + 3] = excl;
}

__global__ void k_scan2(int* __restrict__ bsum, int nb) {
    int t = threadIdx.x; // single wave of 64; nb <= 64
    int v = (t < nb) ? bsum[t] : 0;
    int orig = v;
    for (int off = 1; off < 64; off <<= 1) {
        int y = __shfl_up(v, off);
        if (t >= off) v += y;
    }
    if (t < nb) bsum[t] = v - orig; // exclusive prefix
}

__global__ __launch_bounds__(256) void k_scan3(int* __restrict__ rowptr, const int* __restrict__ bsum,
                                               int* __restrict__ cursor) {
    int i = blockIdx.x * 256 + threadIdx.x;
    if (i < NN) {
        int r = rowptr[i] + bsum[i >> 10];
        rowptr[i] = r;
        cursor[i] = r;
    }
    if (i == NN) rowptr[NN] = ET_;
}

// slot payload is just the src node (edge id not needed: alpha is emitted edge-ordered).
__global__ __launch_bounds__(256) void k_scatter(const int* __restrict__ ei, int* __restrict__ cursor,
                                                 int* __restrict__ esrc) {
    int e = blockIdx.x * 256 + threadIdx.x;
    if (e >= ET_) return;
    int s, d;
    if (e < EE) { s = ei[e]; d = ei[EE + e]; } else { s = e - EE; d = e - EE; }
    int slot = atomicAdd(&cursor[d], 1);
    esrc[slot] = s;
}

// ---------------- register-resident MFMA GEMM: C[M,160] = A[M,K] @ W[K,160] ----------------
// NO LDS, NO barriers, NO scattered loads. A is ALWAYS fragment-packed
// (layer 1: k_hist_conv; layers 2/3: k_att_agg emits packed directly) — every A
// load is a contiguous 4KB block-burst, every B load a 1KB wave burst.
// Fused epilogues:
//  - asrc/adst -> als/ald: per-row per-head attention dots (GAT layers)
//  - batch+pooled: global mean-pool partial sums (readout GEMM)
static __device__ __forceinline__ void gemm_body(int blk,
                                                 const ab8* __restrict__ Apk,
                                                 const ab8* __restrict__ Bpk, int nk,
                                                 float* __restrict__ C, __hip_bfloat16* __restrict__ Cb,
                                                 int M,
                                                 const float* __restrict__ bias, int act,
                                                 const float* __restrict__ asrc, const float* __restrict__ adst,
                                                 float* __restrict__ als_o, float* __restrict__ ald_o,
                                                 const int* __restrict__ batch_p, float* __restrict__ pooled) {
    int tid  = threadIdx.x;
    int lane = tid & 63;
    int w    = tid >> 6;
    int fr   = lane & 15;        // fragment row/col index
    int q    = lane >> 4;        // quad: k-subtile for inputs, row-subtile for output
    int row0 = blk * 64;

    f4 acc[10];
#pragma unroll
    for (int t = 0; t < 10; t++) acc[t] = (f4)0.f;

    const ab8* bb  = Bpk + lane;
    const ab8* apk = Apk + (size_t)blk * nk * 256 + tid;

    ab8 bcur[10], bnx[10];
#pragma unroll
    for (int t = 0; t < 10; t++) bcur[t] = bb[t * 64];
    ab8 a0 = apk[0];
    ab8 a1 = apk[256];               // nk >= 5 always
    for (int s = 0; s < nk; s++) {
        if (s + 1 < nk) {
#pragma unroll
            for (int t = 0; t < 10; t++) bnx[t] = bb[((s + 1) * 10 + t) * 64];
        }
        ab8 a2 = (ab8)0;
        if (s + 2 < nk) a2 = apk[(s + 2) * 256];
#pragma unroll
        for (int t = 0; t < 10; t++)
            acc[t] = __builtin_amdgcn_mfma_f32_16x16x32_bf16(a0, bcur[t], acc[t], 0, 0, 0);
        a0 = a1; a1 = a2;
#pragma unroll
        for (int t = 0; t < 10; t++) bcur[t] = bnx[t];
    }

    // ---- fused per-node attention dots: als/ald (GAT layers), stride-8 rows ----
    if (als_o) {
        float av_s[10], av_d[10];
#pragma unroll
        for (int t = 0; t < 10; t++) { av_s[t] = asrc[t * 16 + fr]; av_d[t] = adst[t * 16 + fr]; }
#pragma unroll
        for (int i = 0; i < 4; i++) {
            int r = row0 + w * 16 + q * 4 + i;
            float ps[5], pd[5];
#pragma unroll
            for (int h = 0; h < 5; h++) {
                ps[h] = acc[2 * h][i] * av_s[2 * h] + acc[2 * h + 1][i] * av_s[2 * h + 1];
                pd[h] = acc[2 * h][i] * av_d[2 * h] + acc[2 * h + 1][i] * av_d[2 * h + 1];
            }
#pragma unroll
            for (int off = 8; off >= 1; off >>= 1)
#pragma unroll
                for (int h = 0; h < 5; h++) {
                    ps[h] += __shfl_xor(ps[h], off);
                    pd[h] += __shfl_xor(pd[h], off);
                }
            if (fr == 0 && r < M) {
#pragma unroll
                for (int h = 0; h < 5; h++) {
                    als_o[(size_t)r * 8 + h] = ps[h];
                    ald_o[(size_t)r * 8 + h] = pd[h];
                }
            }
        }
    }

    // ---- pool setup (readout GEMM): block-uniform-graph fast path ----
    int gu = -2;
    if (pooled) {
        int rhi = row0 + 63; if (rhi >= M) rhi = M - 1;
        int gl = batch_p[row0], gh = batch_p[rhi];
        gu = (gl == gh) ? gl : -1;
    }
    float psum[10];
#pragma unroll
    for (int t = 0; t < 10; t++) psum[t] = 0.f;

    // ---- epilogue: C/D layout col=lane&15, row=(lane>>4)*4+reg ----
    int rbase = row0 + w * 16 + q * 4;
#pragma unroll
    for (int t = 0; t < 10; t++) {
        int col = t * 16 + fr;
        float bv = bias ? bias[col] : 0.f;
#pragma unroll
        for (int i = 0; i < 4; i++) {
            int r = rbase + i;
            float v = acc[t][i] + bv;
            if (act) v = v > 0.f ? v : 0.01f * v;
            if (r < M) {
                if (C)  C[(size_t)r * HID_ + col] = v;
                if (Cb) *reinterpret_cast<unsigned short*>(&Cb[(size_t)r * HID_ + col]) = f2bf(v);
                if (gu >= 0) psum[t] += v;
                else if (gu == -1) atomicAdd(&pooled[batch_p[r] * HID_ + col], v);
            }
        }
    }
    if (gu >= 0) {
#pragma unroll
        for (int t = 0; t < 10; t++) {
            psum[t] += __shfl_xor(psum[t], 16);
            psum[t] += __shfl_xor(psum[t], 32);
        }
        if (q == 0) {
#pragma unroll
            for (int t = 0; t < 10; t++)
                atomicAdd(&pooled[gu * HID_ + t * 16 + fr], psum[t]);
        }
    }
}

__global__ __launch_bounds__(256) void k_gemm_pk(const ab8* __restrict__ Apk,
                                                 const ab8* __restrict__ Bpk, int nk,
                                                 float* __restrict__ C, __hip_bfloat16* __restrict__ Cb,
                                                 int M,
                                                 const float* __restrict__ bias, int act,
                                                 const float* __restrict__ asrc, const float* __restrict__ adst,
                                                 float* __restrict__ als_o, float* __restrict__ ald_o,
                                                 const int* __restrict__ batch_p, float* __restrict__ pooled) {
    gemm_body(blockIdx.x, Apk, Bpk, nk, C, Cb, M, bias, act, asrc, adst, als_o, ald_o, batch_p, pooled);
}

// ---------- edge-ordered alpha emission (device body): coalesced 20B/edge writes ----------
static __device__ __forceinline__ void alpha_body(int e, const int* __restrict__ ei,
                                                  const float* __restrict__ als, const float* __restrict__ ald,
                                                  const float* __restrict__ invb,
                                                  float* __restrict__ alpha_out) {
    if (e >= ET_) return;
    int s, d;
    if (e < EE) { s = ei[e]; d = ei[EE + e]; } else { s = e - EE; d = e - EE; }
    const float* as = &als[(size_t)s * 8];
    float4 a4 = *reinterpret_cast<const float4*>(as);
    float  a5 = as[4];
    float asv[5] = {a4.x, a4.y, a4.z, a4.w, a5};
    const float* adp = &ald[(size_t)d * 8];
    float4 d4 = *reinterpret_cast<const float4*>(adp);
    float  d5 = adp[4];
    float adv[5] = {d4.x, d4.y, d4.z, d4.w, d5};
    const float* ip = &invb[(size_t)d * 8];
    float4 i4 = *reinterpret_cast<const float4*>(ip);
    float  i5 = ip[4];
    float ivv[5] = {i4.x, i4.y, i4.z, i4.w, i5};
    float* ao = &alpha_out[(size_t)e * 5];
#pragma unroll
    for (int h = 0; h < 5; h++) {
        float l = asv[h] + adv[h];
        l = l > 0.f ? l : 0.2f * l;
        float ex = __expf(fminf(l, 60.f));
        ao[h] = ex * ivv[h];
    }
}

// ---------- fused: K=160 GEMM (this layer) + alpha emission (previous layer) ----------
// Blocks [0,GB1): gemm (reads xpk, writes hbuf/xo + NEXT-layer dots als_o/ald_o).
// Blocks [GB1, GB1+EBH): alpha for the PREVIOUS layer (reads als_r/ald_r/invb —
// distinct ping-pong buffers, so no race with the gemm's dot writes).
// The alpha work fills CUs the 782-block latency-bound GEMM leaves idle.
__global__ __launch_bounds__(256) void k_gemm_alpha(const ab8* __restrict__ Apk,
                                                    const ab8* __restrict__ Bpk, int nk,
                                                    float* __restrict__ C, __hip_bfloat16* __restrict__ Cb,
                                                    int M,
                                                    const float* __restrict__ bias, int act,
                                                    const float* __restrict__ asrc, const float* __restrict__ adst,
                                                    float* __restrict__ als_o, float* __restrict__ ald_o,
                                                    const int* __restrict__ batch_p, float* __restrict__ pooled,
                                                    const int* __restrict__ ei,
                                                    const float* __restrict__ als_r, const float* __restrict__ ald_r,
                                                    const float* __restrict__ invb, float* __restrict__ alpha_out) {
    if (blockIdx.x < GB1) {
        gemm_body(blockIdx.x, Apk, Bpk, nk, C, Cb, M, bias, act, asrc, adst, als_o, ald_o, batch_p, pooled);
    } else {
        int e = (blockIdx.x - GB1) * 256 + threadIdx.x;
        alpha_body(e, ei, als_r, ald_r, invb, alpha_out);
    }
}

// ---------- fused edge softmax + aggregation + bias + leaky + LayerNorm ----------
// One wave per destination node. Channel map: lane l owns ch {2l,2l+1}; lanes 0..15
// additionally own {128+2l,128+2l+1} (head 4). Aggregation is 4-edge unrolled with
// pre-normalized LDS weights. Output is emitted DIRECTLY in the GEMM's packed-A
// fragment layout (shuffles assemble 20x16B chunks; lanes 0..19 store) so the
// downstream K=160 GEMMs read fully-coalesced A.
__global__ __launch_bounds__(256) void k_att_agg(const int* __restrict__ rowptr,
                                                 const int* __restrict__ esrc,
                                                 const float* __restrict__ als, const float* __restrict__ ald,
                                                 const __hip_bfloat16* __restrict__ hmat,
                                                 float* __restrict__ alphap,      // [ET_*5] overflow scratch
                                                 float* __restrict__ invb,        // [NN*8] per-node 1/sum
                                                 const float* __restrict__ bias,
                                                 const float* __restrict__ lns, const float* __restrict__ lnb,
                                                 uint4* __restrict__ xpk) {       // packed-A output
    __shared__ float sExp[4][64 * 5];
    __shared__ int   sSrc[4][64];
    int wv   = threadIdx.x >> 6;
    int lane = threadIdx.x & 63;
    int node = blockIdx.x * 4 + wv;
    if (node >= NN) return;
    int start = rowptr[node], end = rowptr[node + 1];
    int deg = end - start;
    bool fits = (deg <= 64);
    float4 dd4 = *reinterpret_cast<const float4*>(&ald[(size_t)node * 8]);
    float  dd5 = ald[(size_t)node * 8 + 4];
    float ad[5] = {dd4.x, dd4.y, dd4.z, dd4.w, dd5};

    // ---- pass 1: exp(leaky(logit)), lane-parallel over edges ----
    float sm[5] = {0.f, 0.f, 0.f, 0.f, 0.f};
    for (int j = start + lane; j < end; j += 64) {
        int sy = esrc[j];
        int idx = j - start;
        if (fits) sSrc[wv][idx] = sy;
        const float* as = &als[(size_t)sy * 8];
        float4 a4 = *reinterpret_cast<const float4*>(as);
        float  a5 = as[4];
        float asv[5] = {a4.x, a4.y, a4.z, a4.w, a5};
#pragma unroll
        for (int h = 0; h < 5; h++) {
            float l = asv[h] + ad[h];
            l = l > 0.f ? l : 0.2f * l;
            float ex = __expf(fminf(l, 60.f));
            sm[h] += ex;
            if (fits) sExp[wv][idx * 5 + h] = ex;
            else      alphap[(size_t)j * 5 + h] = ex;
        }
    }
#pragma unroll
    for (int off = 32; off >= 1; off >>= 1)
#pragma unroll
        for (int h = 0; h < 5; h++) sm[h] += __shfl_xor(sm[h], off);
    float inv[5];
#pragma unroll
    for (int h = 0; h < 5; h++) inv[h] = 1.f / (sm[h] + 1e-16f);
    if (lane == 0) {
        float* ip = &invb[(size_t)node * 8];
        ip[0] = inv[0]; ip[1] = inv[1]; ip[2] = inv[2]; ip[3] = inv[3]; ip[4] = inv[4];
    }
    // pre-normalize LDS weights (same product as per-use multiply -> bit-identical)
    if (fits && lane < deg) {
#pragma unroll
        for (int h = 0; h < 5; h++) sExp[wv][lane * 5 + h] *= inv[h];
    }

    int h0 = lane >> 4;            // head of ch pair (2l,2l+1): 0..3
    bool lo16 = lane < 16;         // lanes 0..15 own head-4 pair {128+2l,128+2l+1}
    int c01 = 2 * lane;            // first ch pair
    int c2  = 128 + 2 * lane;      // second ch pair (lo16 only; 128..158)
    float2 A0 = make_float2(0.f, 0.f), A1 = make_float2(0.f, 0.f);
    float2 A2 = make_float2(0.f, 0.f), A3 = make_float2(0.f, 0.f);
    float2 H0 = make_float2(0.f, 0.f), H1 = make_float2(0.f, 0.f);
    float2 H2 = make_float2(0.f, 0.f), H3 = make_float2(0.f, 0.f);

    if (fits) {
        // ---- aggregation: 4-edge unrolled, ch pairs across lanes ----
        int idx = 0;
        for (; idx + 3 < deg; idx += 4) {
            int s0 = sSrc[wv][idx], s1 = sSrc[wv][idx + 1];
            int s2 = sSrc[wv][idx + 2], s3 = sSrc[wv][idx + 3];
            float w0 = sExp[wv][(idx + 0) * 5 + h0];
            float w1 = sExp[wv][(idx + 1) * 5 + h0];
            float w2 = sExp[wv][(idx + 2) * 5 + h0];
            float w3 = sExp[wv][(idx + 3) * 5 + h0];
            const unsigned short* r0 = (const unsigned short*)&hmat[(size_t)s0 * HID_];
            const unsigned short* r1 = (const unsigned short*)&hmat[(size_t)s1 * HID_];
            const unsigned short* r2 = (const unsigned short*)&hmat[(size_t)s2 * HID_];
            const unsigned short* r3 = (const unsigned short*)&hmat[(size_t)s3 * HID_];
            float2 f0 = bf2f2(*reinterpret_cast<const uint32_t*>(&r0[c01]));
            float2 f1 = bf2f2(*reinterpret_cast<const uint32_t*>(&r1[c01]));
            float2 f2 = bf2f2(*reinterpret_cast<const uint32_t*>(&r2[c01]));
            float2 f3 = bf2f2(*reinterpret_cast<const uint32_t*>(&r3[c01]));
            A0.x += w0 * f0.x; A0.y += w0 * f0.y;
            A1.x += w1 * f1.x; A1.y += w1 * f1.y;
            A2.x += w2 * f2.x; A2.y += w2 * f2.y;
            A3.x += w3 * f3.x; A3.y += w3 * f3.y;
            if (lo16) {
                float u0 = sExp[wv][(idx + 0) * 5 + 4];
                float u1 = sExp[wv][(idx + 1) * 5 + 4];
                float u2 = sExp[wv][(idx + 2) * 5 + 4];
                float u3 = sExp[wv][(idx + 3) * 5 + 4];
                float2 g0 = bf2f2(*reinterpret_cast<const uint32_t*>(&r0[c2]));
                float2 g1 = bf2f2(*reinterpret_cast<const uint32_t*>(&r1[c2]));
                float2 g2 = bf2f2(*reinterpret_cast<const uint32_t*>(&r2[c2]));
                float2 g3 = bf2f2(*reinterpret_cast<const uint32_t*>(&r3[c2]));
                H0.x += u0 * g0.x; H0.y += u0 * g0.y;
                H1.x += u1 * g1.x; H1.y += u1 * g1.y;
                H2.x += u2 * g2.x; H2.y += u2 * g2.y;
                H3.x += u3 * g3.x; H3.y += u3 * g3.y;
            }
        }
        for (; idx < deg; idx++) {
            int s0 = sSrc[wv][idx];
            float w0 = sExp[wv][idx * 5 + h0];
            const unsigned short* r0 = (const unsigned short*)&hmat[(size_t)s0 * HID_];
            float2 f0 = bf2f2(*reinterpret_cast<const uint32_t*>(&r0[c01]));
            A0.x += w0 * f0.x; A0.y += w0 * f0.y;
            if (lo16) {
                float u0 = sExp[wv][idx * 5 + 4];
                float2 g0 = bf2f2(*reinterpret_cast<const uint32_t*>(&r0[c2]));
                H0.x += u0 * g0.x; H0.y += u0 * g0.y;
            }
        }
    } else {
        // ---- overflow path (deg > 64): exp staged in global scratch ----
        for (int j = start; j < end; j++) {
            int s0 = esrc[j];
            float w0 = alphap[(size_t)j * 5 + h0] * inv[h0];
            const unsigned short* r0 = (const unsigned short*)&hmat[(size_t)s0 * HID_];
            float2 f0 = bf2f2(*reinterpret_cast<const uint32_t*>(&r0[c01]));
            A0.x += w0 * f0.x; A0.y += w0 * f0.y;
            if (lo16) {
                float u0 = alphap[(size_t)j * 5 + 4] * inv[4];
                float2 g0 = bf2f2(*reinterpret_cast<const uint32_t*>(&r0[c2]));
                H0.x += u0 * g0.x; H0.y += u0 * g0.y;
            }
        }
    }
    float2 A = make_float2(A0.x + A1.x + A2.x + A3.x, A0.y + A1.y + A2.y + A3.y);
    float2 Hh = make_float2(H0.x + H1.x + H2.x + H3.x, H0.y + H1.y + H2.y + H3.y);

    // ---- bias + leaky(0.01) + LayerNorm ----
    float2 bb = *reinterpret_cast<const float2*>(&bias[c01]);
    float v0 = A.x + bb.x;  v0 = v0 > 0.f ? v0 : 0.01f * v0;
    float v1 = A.y + bb.y;  v1 = v1 > 0.f ? v1 : 0.01f * v1;
    float v2 = 0.f, v3 = 0.f;
    if (lo16) {
        float2 b2 = *reinterpret_cast<const float2*>(&bias[c2]);
        v2 = Hh.x + b2.x; v2 = v2 > 0.f ? v2 : 0.01f * v2;
        v3 = Hh.y + b2.y; v3 = v3 > 0.f ? v3 : 0.01f * v3;
    }
    float s  = v0 + v1 + v2 + v3;
    float sq = v0 * v0 + v1 * v1 + v2 * v2 + v3 * v3;
#pragma unroll
    for (int off = 32; off >= 1; off >>= 1) {
        s  += __shfl_xor(s, off);
        sq += __shfl_xor(sq, off);
    }
    float m = s * (1.f / 160.f);
    float r = rsqrtf(sq * (1.f / 160.f) - m * m + 1e-5f);
    uint32_t pk1, pk2 = 0u;
    {
        float2 sc = *reinterpret_cast<const float2*>(&lns[c01]);
        float2 bi = *reinterpret_cast<const float2*>(&lnb[c01]);
        pk1 = (uint32_t)f2bf((v0 - m) * r * sc.x + bi.x)
            | ((uint32_t)f2bf((v1 - m) * r * sc.y + bi.y) << 16);
    }
    if (lo16) {
        float2 sc = *reinterpret_cast<const float2*>(&lns[c2]);
        float2 bi = *reinterpret_cast<const float2*>(&lnb[c2]);
        pk2 = (uint32_t)f2bf((v2 - m) * r * sc.x + bi.x)
            | ((uint32_t)f2bf((v3 - m) * r * sc.y + bi.y) << 16);
    }
    // ---- repack node row into GEMM fragment chunks (20 x 16B) ----
    // chunk j covers ch 8j..8j+7 = pairs 4j..4j+3 (pk1 of lanes 4j.. if j<16,
    // else pk2 of lanes 4(j-16)..). srcb clamped so every __shfl lane index is
    // in range for all 64 lanes (results discarded for j>=20).
    int j = lane;
    int srcb = (j < 16) ? (4 * j) : (4 * ((j - 16) & 15));
    uint32_t a0w = __shfl(pk1, srcb + 0), a1w = __shfl(pk1, srcb + 1);
    uint32_t a2w = __shfl(pk1, srcb + 2), a3w = __shfl(pk1, srcb + 3);
    uint32_t b0w = __shfl(pk2, srcb + 0), b1w = __shfl(pk2, srcb + 1);
    uint32_t b2w = __shfl(pk2, srcb + 2), b3w = __shfl(pk2, srcb + 3);
    if (j < 20) {
        uint4 val;
        val.x = (j < 16) ? a0w : b0w;
        val.y = (j < 16) ? a1w : b1w;
        val.z = (j < 16) ? a2w : b2w;
        val.w = (j < 16) ? a3w : b3w;
        int blk = node >> 6, wq = (node >> 4) & 3, fr = node & 15;
        int ks = j >> 2, q = j & 3;
        size_t cidx = (size_t)(blk * NK2 + ks) * 256 + wq * 64 + q * 16 + fr;
        xpk[cidx] = val;
    }
}

// ---------------- readout MLP (single block) ----------------
__global__ __launch_bounds__(256) void k_mlp(const float* __restrict__ pooled, const int* __restrict__ batch,
                                             const float* __restrict__ W1, const float* __restrict__ b1,
                                             const float* __restrict__ lns, const float* __restrict__ lnb,
                                             const float* __restrict__ W2, const float* __restrict__ b2,
                                             float* __restrict__ rec) {
    __shared__ float P[GG][HID_];
    __shared__ float Z[GG][HID_];
    __shared__ float mu[GG], rr[GG], ic[GG];
    int t = threadIdx.x;
    if (t < GG) {
        int lo = lbound_i(batch, NN, t), hi = lbound_i(batch, NN, t + 1);
        ic[t] = 1.f / fmaxf((float)(hi - lo), 1.f);
    }
    __syncthreads();
    for (int i = t; i < GG * HID_; i += 256) P[i / HID_][i % HID_] = pooled[i] * ic[i / HID_];
    __syncthreads();
    for (int i = t; i < GG * HID_; i += 256) {
        int g = i / HID_, j = i % HID_;
        float acc = b1[j];
        for (int k = 0; k < HID_; k++) acc += P[g][k] * W1[k * HID_ + j];
        Z[g][j] = acc;
    }
    __syncthreads();
    if (t < GG) {
        float s = 0.f, sq = 0.f;
        for (int k = 0; k < HID_; k++) { float z = Z[t][k]; s += z; sq += z * z; }
        float m = s / (float)HID_;
        mu[t] = m;
        rr[t] = rsqrtf(sq / (float)HID_ - m * m + 1e-5f);
    }
    __syncthreads();
    for (int i = t; i < GG * HID_; i += 256) {
        int g = i / HID_, j = i % HID_;
        float z = (Z[g][j] - mu[g]) * rr[g] * lns[j] + lnb[j];
        Z[g][j] = fmaxf(z, 0.f);
    }
    __syncthreads();
    for (int i = t; i < GG * NC_; i += 256) {
        int g = i / NC_, j = i % NC_;
        float acc = b2[j];
        for (int k = 0; k < HID_; k++) acc += Z[g][k] * W2[k * NC_ + j];
        rec[g * NC_ + j] = acc;
    }
}

extern "C" void kernel_launch(void* const* d_in, const int* in_sizes, int n_in,
                              void* d_out, int out_size, void* d_ws, size_t ws_size,
                              hipStream_t stream) {
    const float* x    = (const float*)d_in[0];
    const int*   ei   = (const int*)d_in[1];
    const int*   batch= (const int*)d_in[2];
    const float* W1   = (const float*)d_in[3];
    const float* as1  = (const float*)d_in[4];
    const float* ad1  = (const float*)d_in[5];
    const float* b1   = (const float*)d_in[6];
    const float* ln1s = (const float*)d_in[7];
    const float* ln1b = (const float*)d_in[8];
    const float* W2   = (const float*)d_in[9];
    const float* as2  = (const float*)d_in[10];
    const float* ad2  = (const float*)d_in[11];
    const float* b2   = (const float*)d_in[12];
    const float* ln2s = (const float*)d_in[13];
    const float* ln2b = (const float*)d_in[14];
    const float* Wm   = (const float*)d_in[15];
    const float* bm   = (const float*)d_in[16];
    const float* Wm1  = (const float*)d_in[17];
    const float* bm1  = (const float*)d_in[18];
    const float* ln3s = (const float*)d_in[19];
    const float* ln3b = (const float*)d_in[20];
    const float* Wm2  = (const float*)d_in[21];
    const float* bm2  = (const float*)d_in[22];

    float* out    = (float*)d_out;
    float* xo     = out;                              // N*160
    float* rec    = out + (size_t)NN * HID_;          // 8*20
    float* alpha1 = rec + GG * NC_;                   // ET*5
    float* alpha2 = alpha1 + (size_t)ET_ * 5;         // ET*5

    char* w = (char*)d_ws;
    auto carve = [&](size_t bytes) { char* p = w; w += (bytes + 255) & ~(size_t)255; return p; };
    int*   deg    = (int*)carve((size_t)NN * 4);
    int*   rowptr = (int*)carve((size_t)(NN + 1) * 4);
    int*   cursor = (int*)carve((size_t)NN * 4);
    int*   esrc   = (int*)carve((size_t)ET_ * 4);
    int*   bsum   = (int*)carve(64 * 4);
    __hip_bfloat16* hbuf = (__hip_bfloat16*)carve((size_t)NN * HID_ * 2);
    uint4* xpk    = (uint4*)carve((size_t)GB1 * NK2 * 256 * 16);  // packed attn output (16MB)
    float* alphap = (float*)carve((size_t)ET_ * 5 * 4);
    float* als1   = (float*)carve((size_t)NN * 8 * 4);   // ping-pong dot buffers:
    float* ald1   = (float*)carve((size_t)NN * 8 * 4);   // layer-1 dots live while the
    float* als2   = (float*)carve((size_t)NN * 8 * 4);   // fused gemm2 writes layer-2
    float* ald2   = (float*)carve((size_t)NN * 8 * 4);   // dots (no race)
    float* invb   = (float*)carve((size_t)NN * 8 * 4);
    float* pooled = (float*)carve((size_t)GG * HID_ * 4);
    ab8*   B1pk   = (ab8*)carve((size_t)NK1 * 10 * 64 * 16);     // 160 KB
    ab8*   B2pk   = (ab8*)carve((size_t)NK2 * 10 * 64 * 16);     // 50 KB
    ab8*   Bmpk   = (ab8*)carve((size_t)NK2 * 10 * 64 * 16);     // 50 KB
    // Apk (51.25MB) lives in d_out: dead after the layer-1 GEMM; alpha1/xo writes
    // to that region all happen in later dispatches.
    ab8*   Apk    = (ab8*)d_out;                                 // GB1*NK1*256*16 B

    // ---- 1. prep: zero deg/pooled + pack all B weights ----
    k_prep0<<<(NN + 255) / 256, 256, 0, stream>>>(W1, B1pk, W2, B2pk, Wm, Bmpk, pooled, deg);

    // ---- 2. fused hist + packed-A conversion ----
    k_hist_conv<<<EBH + GB1 * NK1, 256, 0, stream>>>(ei, deg, x, Apk);

    // ---- 3-6. CSR scans + scatter ----
    int nb = (NN + 1023) / 1024;
    k_scan1<<<nb, 256, 0, stream>>>(deg, rowptr, bsum);
    k_scan2<<<1, 64, 0, stream>>>(bsum, nb);
    k_scan3<<<(NN + 1 + 255) / 256, 256, 0, stream>>>(rowptr, bsum, cursor);
    k_scatter<<<EBH, 256, 0, stream>>>(ei, cursor, esrc);

    const int NWB = (NN + 3) / 4;         // wave-per-node blocks (4 waves/block)

    // ---- 7-8. layer 1 ----
    k_gemm_pk<<<GB1, 256, 0, stream>>>(Apk, B1pk, NK1, nullptr, hbuf, NN, nullptr, 0,
                                       as1, ad1, als1, ald1, nullptr, nullptr);
    k_att_agg<<<NWB, 256, 0, stream>>>(rowptr, esrc, als1, ald1, hbuf, alphap, invb,
                                       b1, ln1s, ln1b, xpk);

    // ---- 9. fused: layer-2 GEMM + alpha1 emission ----
    k_gemm_alpha<<<GB1 + EBH, 256, 0, stream>>>((const ab8*)xpk, B2pk, NK2, nullptr, hbuf, NN,
                                                nullptr, 0, as2, ad2, als2, ald2, nullptr, nullptr,
                                                ei, als1, ald1, invb, alpha1);

    // ---- 10. layer-2 attention ----
    k_att_agg<<<NWB, 256, 0, stream>>>(rowptr, esrc, als2, ald2, hbuf, alphap, invb,
                                       b2, ln2s, ln2b, xpk);

    // ---- 11. fused: readout GEMM (+mean-pool partials) + alpha2 emission ----
    k_gemm_alpha<<<GB1 + EBH, 256, 0, stream>>>((const ab8*)xpk, Bmpk, NK2, xo, nullptr, NN,
                                                bm, 1, nullptr, nullptr, nullptr, nullptr, batch, pooled,
                                                ei, als2, ald2, invb, alpha2);

    // ---- 12. readout MLP ----
    k_mlp<<<1, 256, 0, stream>>>(pooled, batch, Wm1, bm1, ln3s, ln3b, Wm2, bm2, rec);
}

// Round 8
// 600.235 us; speedup vs baseline: 1.0716x; 1.0200x over previous
//
#include <hip/hip_runtime.h>
#include <hip/hip_bf16.h>
#include <cstdint>
#include <cstddef>

#define NN   50000
#define EE   800000
#define ET_  (EE + NN)      // 850000 edges incl. self-loops
#define FIN  500
#define HID_ 160
#define NC_  20
#define GG   8
#define GB1  ((NN + 63) / 64)   // 782 GEMM blocks (64 rows each)
#define NK1  16                 // layer-1 k-steps (K=500 padded to 512)
#define NK2  5                  // K=160 k-steps
#define EBH  ((ET_ + 255) / 256) // 3321 edge-parallel blocks

typedef __attribute__((ext_vector_type(8))) short ab8;   // 8 bf16 (4 VGPRs)
typedef __attribute__((ext_vector_type(4))) float f4;    // MFMA accumulator

static __device__ __forceinline__ unsigned short f2bf(float v) {
    union { float f; uint32_t u; } c; c.f = v;
    uint32_t r = c.u + 0x7FFFu + ((c.u >> 16) & 1u);  // RNE
    return (unsigned short)(r >> 16);
}

static __device__ __forceinline__ float2 bf2f2(uint32_t u) {
    // u holds bf16 pair (lo = even ch, hi = odd ch)
    union { uint32_t u; float f; } a, b;
    a.u = u << 16;
    b.u = u & 0xffff0000u;
    return make_float2(a.f, b.f);
}

static __device__ __forceinline__ int lbound_i(const int* arr, int n, int val) {
    int lo = 0, hi = n;
    while (lo < hi) { int mid = (lo + hi) >> 1; if (arr[mid] < val) lo = mid + 1; else hi = mid; }
    return lo;
}

// ---------------- prep0: zero deg + pooled, pack B for all three GEMMs ----------------
// Bpk chunk (s,t,l): the 16B ab8 that lane l feeds MFMA t at k-step s.
// chunk value = W^T[n = t*16 + (l&15)][k0 = s*32 + (l>>4)*8 .. +8], zero-padded past K.
__global__ __launch_bounds__(256) void k_prep0(const float* __restrict__ W1, ab8* __restrict__ B1,
                                               const float* __restrict__ W2, ab8* __restrict__ B2,
                                               const float* __restrict__ Wm, ab8* __restrict__ Bm,
                                               float* __restrict__ pooled, int* __restrict__ deg) {
    int idx = blockIdx.x * 256 + threadIdx.x;      // grid covers NN threads
    if (idx < NN) deg[idx] = 0;
    if (idx < GG * HID_) pooled[idx] = 0.f;
    const int C1 = NK1 * 10 * 64;      // 10240 chunks
    const int C2 = NK2 * 10 * 64;      // 3200 chunks
    const float* W; ab8* Bo; int K, cidx;
    if (idx < C1)                { W = W1; Bo = B1; K = FIN;  cidx = idx; }
    else if (idx < C1 + C2)      { W = W2; Bo = B2; K = HID_; cidx = idx - C1; }
    else if (idx < C1 + 2 * C2)  { W = Wm; Bo = Bm; K = HID_; cidx = idx - C1 - C2; }
    else return;
    int s = cidx / 640, r = cidx % 640;
    int t = r >> 6, l = r & 63;
    int fr = l & 15, q = l >> 4;
    int n  = t * 16 + fr;
    int k0 = s * 32 + q * 8;
    unsigned short pk[8];
#pragma unroll
    for (int j = 0; j < 8; j++) {
        int k = k0 + j;
        pk[j] = (k < K) ? f2bf(W[(size_t)k * HID_ + n]) : (unsigned short)0;
    }
    Bo[cidx] = *reinterpret_cast<ab8*>(pk);
}

// ---------------- fused: streaming x->packed-A conversion + edge histogram ----------------
// Blocks [0,GB1): conv — one block per GEMM-blk, two 32-row halves. Reads its
// 128KB row-slab as CONTIGUOUS float4 streams (the old per-chunk mapping read 16
// distinct 2000B rows per wave-load -> 2.15TB/s; this streams at full rate),
// permutes to fragment layout in a 32KB LDS buffer, writes out 2KB bursts.
// LDS is XOR-swizzled by ((s<<2)|q)&7 (bijective) — unswizzled, a wave filling one
// row hits only 2 banks (32-way conflict); swizzled, writes spread over all 32.
// Blocks [GB1, GB1+EBH): k_hist (atomic deg counts) co-scheduled.
// Apk lives in the first 51.25MB of d_out (dead until later kernels).
__global__ __launch_bounds__(256) void k_hist_conv(const int* __restrict__ ei, int* __restrict__ deg,
                                                   const float* __restrict__ x, ab8* __restrict__ Apk) {
    if (blockIdx.x >= GB1) {
        int e = (blockIdx.x - GB1) * 256 + threadIdx.x;
        if (e >= ET_) return;
        int d = (e < EE) ? ei[EE + e] : (e - EE);
        atomicAdd(&deg[d], 1);
        return;
    }
    __shared__ uint2 lds2[4096];                 // 32KB: 2048 chunks x 16B
    int blk = blockIdx.x;
    int tid = threadIdx.x;
    const float4* xf4 = (const float4*)x;        // row stride 125 float4 (2000B, 16B-aligned)
    uint4* ap4 = (uint4*)Apk;
#pragma unroll
    for (int h = 0; h < 2; h++) {
        // zero (covers k>=FIN pad and rows>=NN)
        for (int i = tid; i < 4096; i += 256) lds2[i] = make_uint2(0u, 0u);
        __syncthreads();
        // fill: stream 32 rows x 125 float4 contiguously
        int rbase = blk * 64 + h * 32;
        for (int i = tid; i < 4000; i += 256) {
            int rl = i / 125, j = i - rl * 125;
            int g = rbase + rl;
            if (g < NN) {
                float4 v = xf4[(size_t)g * 125 + j];
                uint32_t lo = (uint32_t)f2bf(v.x) | ((uint32_t)f2bf(v.y) << 16);
                uint32_t hi = (uint32_t)f2bf(v.z) | ((uint32_t)f2bf(v.w) << 16);
                int k = j * 4;
                int s = k >> 5, q = (k >> 3) & 3, e2 = (k & 7) >> 2;
                int woff = rl >> 4, fr = rl & 15;
                int idx = s * 128 + woff * 64 + q * 16 + fr;
                int p = idx ^ (((s << 2) | q) & 7);
                lds2[2 * p + e2] = make_uint2(lo, hi);
            }
        }
        __syncthreads();
        // writeout: chunk (s, off) -> Apk[(blk*NK1+s)*256 + h*128 + off], 2KB bursts
        for (int i = tid; i < 2048; i += 256) {
            int s = i >> 7, off = i & 127;
            int q = (off >> 4) & 3;
            int p = i ^ (((s << 2) | q) & 7);
            uint2 a = lds2[2 * p], b = lds2[2 * p + 1];
            ap4[(size_t)(blk * NK1 + s) * 256 + h * 128 + off] = make_uint4(a.x, a.y, b.x, b.y);
        }
        __syncthreads();
    }
}

// ---------------- CSR scans ----------------
__global__ __launch_bounds__(256) void k_scan1(const int* __restrict__ deg, int* __restrict__ rowptr,
                                               int* __restrict__ bsum) {
    __shared__ int s[256];
    int t = threadIdx.x;
    int base = blockIdx.x * 1024 + t * 4;
    int v0 = (base + 0 < NN) ? deg[base + 0] : 0;
    int v1 = (base + 1 < NN) ? deg[base + 1] : 0;
    int v2 = (base + 2 < NN) ? deg[base + 2] : 0;
    int v3 = (base + 3 < NN) ? deg[base + 3] : 0;
    int tot = v0 + v1 + v2 + v3;
    s[t] = tot;
    __syncthreads();
    for (int off = 1; off < 256; off <<= 1) {
        int y = (t >= off) ? s[t - off] : 0;
        __syncthreads();
        s[t] += y;
        __syncthreads();
    }
    int excl = s[t] - tot;
    if (t == 255) bsum[blockIdx.x] = s[255];
    if (base + 0 < NN) rowptr[base + 0] = excl;  excl += v0;
    if (base + 1 < NN) rowptr[base + 1] = excl;  excl += v1;
    if (base + 2 < NN) rowptr[base + 2] = excl;  excl += v2;
    if (base + 3 < NN) rowptr[base + 3] = excl;
}

__global__ void k_scan2(int* __restrict__ bsum, int nb) {
    int t = threadIdx.x; // single wave of 64; nb <= 64
    int v = (t < nb) ? bsum[t] : 0;
    int orig = v;
    for (int off = 1; off < 64; off <<= 1) {
        int y = __shfl_up(v, off);
        if (t >= off) v += y;
    }
    if (t < nb) bsum[t] = v - orig; // exclusive prefix
}

__global__ __launch_bounds__(256) void k_scan3(int* __restrict__ rowptr, const int* __restrict__ bsum,
                                               int* __restrict__ cursor) {
    int i = blockIdx.x * 256 + threadIdx.x;
    if (i < NN) {
        int r = rowptr[i] + bsum[i >> 10];
        rowptr[i] = r;
        cursor[i] = r;
    }
    if (i == NN) rowptr[NN] = ET_;
}

// ---------------- register-resident MFMA GEMM: C[M,160] = A[M,K] @ W[K,160] ----------------
// NO LDS, NO barriers, NO scattered loads. A is ALWAYS fragment-packed
// (layer 1: k_hist_conv; layers 2/3: k_att_agg emits packed directly) — every A
// load is a contiguous 4KB block-burst, every B load a 1KB wave burst.
// Fused epilogues:
//  - asrc/adst -> als/ald: per-row per-head attention dots (GAT layers)
//  - batch+pooled: global mean-pool partial sums (readout GEMM)
static __device__ __forceinline__ void gemm_body(int blk,
                                                 const ab8* __restrict__ Apk,
                                                 const ab8* __restrict__ Bpk, int nk,
                                                 float* __restrict__ C, __hip_bfloat16* __restrict__ Cb,
                                                 int M,
                                                 const float* __restrict__ bias, int act,
                                                 const float* __restrict__ asrc, const float* __restrict__ adst,
                                                 float* __restrict__ als_o, float* __restrict__ ald_o,
                                                 const int* __restrict__ batch_p, float* __restrict__ pooled) {
    int tid  = threadIdx.x;
    int lane = tid & 63;
    int w    = tid >> 6;
    int fr   = lane & 15;        // fragment row/col index
    int q    = lane >> 4;        // quad: k-subtile for inputs, row-subtile for output
    int row0 = blk * 64;

    f4 acc[10];
#pragma unroll
    for (int t = 0; t < 10; t++) acc[t] = (f4)0.f;

    const ab8* bb  = Bpk + lane;
    const ab8* apk = Apk + (size_t)blk * nk * 256 + tid;

    ab8 bcur[10], bnx[10];
#pragma unroll
    for (int t = 0; t < 10; t++) bcur[t] = bb[t * 64];
    ab8 a0 = apk[0];
    ab8 a1 = apk[256];               // nk >= 5 always
    for (int s = 0; s < nk; s++) {
        if (s + 1 < nk) {
#pragma unroll
            for (int t = 0; t < 10; t++) bnx[t] = bb[((s + 1) * 10 + t) * 64];
        }
        ab8 a2 = (ab8)0;
        if (s + 2 < nk) a2 = apk[(s + 2) * 256];
#pragma unroll
        for (int t = 0; t < 10; t++)
            acc[t] = __builtin_amdgcn_mfma_f32_16x16x32_bf16(a0, bcur[t], acc[t], 0, 0, 0);
        a0 = a1; a1 = a2;
#pragma unroll
        for (int t = 0; t < 10; t++) bcur[t] = bnx[t];
    }

    // ---- fused per-node attention dots: als/ald (GAT layers), stride-8 rows ----
    if (als_o) {
        float av_s[10], av_d[10];
#pragma unroll
        for (int t = 0; t < 10; t++) { av_s[t] = asrc[t * 16 + fr]; av_d[t] = adst[t * 16 + fr]; }
#pragma unroll
        for (int i = 0; i < 4; i++) {
            int r = row0 + w * 16 + q * 4 + i;
            float ps[5], pd[5];
#pragma unroll
            for (int h = 0; h < 5; h++) {
                ps[h] = acc[2 * h][i] * av_s[2 * h] + acc[2 * h + 1][i] * av_s[2 * h + 1];
                pd[h] = acc[2 * h][i] * av_d[2 * h] + acc[2 * h + 1][i] * av_d[2 * h + 1];
            }
#pragma unroll
            for (int off = 8; off >= 1; off >>= 1)
#pragma unroll
                for (int h = 0; h < 5; h++) {
                    ps[h] += __shfl_xor(ps[h], off);
                    pd[h] += __shfl_xor(pd[h], off);
                }
            if (fr == 0 && r < M) {
#pragma unroll
                for (int h = 0; h < 5; h++) {
                    als_o[(size_t)r * 8 + h] = ps[h];
                    ald_o[(size_t)r * 8 + h] = pd[h];
                }
            }
        }
    }

    // ---- pool setup (readout GEMM): block-uniform-graph fast path ----
    int gu = -2;
    if (pooled) {
        int rhi = row0 + 63; if (rhi >= M) rhi = M - 1;
        int gl = batch_p[row0], gh = batch_p[rhi];
        gu = (gl == gh) ? gl : -1;
    }
    float psum[10];
#pragma unroll
    for (int t = 0; t < 10; t++) psum[t] = 0.f;

    // ---- epilogue: C/D layout col=lane&15, row=(lane>>4)*4+reg ----
    int rbase = row0 + w * 16 + q * 4;
#pragma unroll
    for (int t = 0; t < 10; t++) {
        int col = t * 16 + fr;
        float bv = bias ? bias[col] : 0.f;
#pragma unroll
        for (int i = 0; i < 4; i++) {
            int r = rbase + i;
            float v = acc[t][i] + bv;
            if (act) v = v > 0.f ? v : 0.01f * v;
            if (r < M) {
                if (C)  C[(size_t)r * HID_ + col] = v;
                if (Cb) *reinterpret_cast<unsigned short*>(&Cb[(size_t)r * HID_ + col]) = f2bf(v);
                if (gu >= 0) psum[t] += v;
                else if (gu == -1) atomicAdd(&pooled[batch_p[r] * HID_ + col], v);
            }
        }
    }
    if (gu >= 0) {
#pragma unroll
        for (int t = 0; t < 10; t++) {
            psum[t] += __shfl_xor(psum[t], 16);
            psum[t] += __shfl_xor(psum[t], 32);
        }
        if (q == 0) {
#pragma unroll
            for (int t = 0; t < 10; t++)
                atomicAdd(&pooled[gu * HID_ + t * 16 + fr], psum[t]);
        }
    }
}

// ---------- fused: layer-1 GEMM + CSR scatter ----------
// Blocks [0,GB1): gemm (reads Apk/B1pk, writes hbuf + layer-1 dots).
// Blocks [GB1, GB1+EBH): scatter (reads ei/cursor, writes esrc) — independent
// outputs; the scatter's scattered-write latency hides under the GEMM.
__global__ __launch_bounds__(256) void k_gemm_scatter(const ab8* __restrict__ Apk,
                                                      const ab8* __restrict__ Bpk, int nk,
                                                      float* __restrict__ C, __hip_bfloat16* __restrict__ Cb,
                                                      int M,
                                                      const float* __restrict__ bias, int act,
                                                      const float* __restrict__ asrc, const float* __restrict__ adst,
                                                      float* __restrict__ als_o, float* __restrict__ ald_o,
                                                      const int* __restrict__ batch_p, float* __restrict__ pooled,
                                                      const int* __restrict__ ei, int* __restrict__ cursor,
                                                      int* __restrict__ esrc) {
    if (blockIdx.x < GB1) {
        gemm_body(blockIdx.x, Apk, Bpk, nk, C, Cb, M, bias, act, asrc, adst, als_o, ald_o, batch_p, pooled);
    } else {
        int e = (blockIdx.x - GB1) * 256 + threadIdx.x;
        if (e >= ET_) return;
        int s, d;
        if (e < EE) { s = ei[e]; d = ei[EE + e]; } else { s = e - EE; d = e - EE; }
        int slot = atomicAdd(&cursor[d], 1);
        esrc[slot] = s;
    }
}

// ---------- edge-ordered alpha emission (device body): coalesced 20B/edge writes ----------
static __device__ __forceinline__ void alpha_body(int e, const int* __restrict__ ei,
                                                  const float* __restrict__ als, const float* __restrict__ ald,
                                                  const float* __restrict__ invb,
                                                  float* __restrict__ alpha_out) {
    if (e >= ET_) return;
    int s, d;
    if (e < EE) { s = ei[e]; d = ei[EE + e]; } else { s = e - EE; d = e - EE; }
    const float* as = &als[(size_t)s * 8];
    float4 a4 = *reinterpret_cast<const float4*>(as);
    float  a5 = as[4];
    float asv[5] = {a4.x, a4.y, a4.z, a4.w, a5};
    const float* adp = &ald[(size_t)d * 8];
    float4 d4 = *reinterpret_cast<const float4*>(adp);
    float  d5 = adp[4];
    float adv[5] = {d4.x, d4.y, d4.z, d4.w, d5};
    const float* ip = &invb[(size_t)d * 8];
    float4 i4 = *reinterpret_cast<const float4*>(ip);
    float  i5 = ip[4];
    float ivv[5] = {i4.x, i4.y, i4.z, i4.w, i5};
    float* ao = &alpha_out[(size_t)e * 5];
#pragma unroll
    for (int h = 0; h < 5; h++) {
        float l = asv[h] + adv[h];
        l = l > 0.f ? l : 0.2f * l;
        float ex = __expf(fminf(l, 60.f));
        ao[h] = ex * ivv[h];
    }
}

// ---------- fused: K=160 GEMM (this layer) + alpha emission (previous layer) ----------
// Blocks [0,GB1): gemm (reads xpk, writes hbuf/xo + NEXT-layer dots als_o/ald_o).
// Blocks [GB1, GB1+EBH): alpha for the PREVIOUS layer (reads als_r/ald_r/invb —
// distinct ping-pong buffers, so no race with the gemm's dot writes).
__global__ __launch_bounds__(256) void k_gemm_alpha(const ab8* __restrict__ Apk,
                                                    const ab8* __restrict__ Bpk, int nk,
                                                    float* __restrict__ C, __hip_bfloat16* __restrict__ Cb,
                                                    int M,
                                                    const float* __restrict__ bias, int act,
                                                    const float* __restrict__ asrc, const float* __restrict__ adst,
                                                    float* __restrict__ als_o, float* __restrict__ ald_o,
                                                    const int* __restrict__ batch_p, float* __restrict__ pooled,
                                                    const int* __restrict__ ei,
                                                    const float* __restrict__ als_r, const float* __restrict__ ald_r,
                                                    const float* __restrict__ invb, float* __restrict__ alpha_out) {
    if (blockIdx.x < GB1) {
        gemm_body(blockIdx.x, Apk, Bpk, nk, C, Cb, M, bias, act, asrc, adst, als_o, ald_o, batch_p, pooled);
    } else {
        int e = (blockIdx.x - GB1) * 256 + threadIdx.x;
        alpha_body(e, ei, als_r, ald_r, invb, alpha_out);
    }
}

// ---------- fused edge softmax + aggregation + bias + leaky + LayerNorm ----------
// One wave per destination node. Channel map: lane l owns ch {2l,2l+1}; lanes 0..15
// additionally own {128+2l,128+2l+1} (head 4). Aggregation is 4-edge unrolled with
// pre-normalized LDS weights. Output is emitted DIRECTLY in the GEMM's packed-A
// fragment layout (shuffles assemble 20x16B chunks; lanes 0..19 store) so the
// downstream K=160 GEMMs read fully-coalesced A.
__global__ __launch_bounds__(256) void k_att_agg(const int* __restrict__ rowptr,
                                                 const int* __restrict__ esrc,
                                                 const float* __restrict__ als, const float* __restrict__ ald,
                                                 const __hip_bfloat16* __restrict__ hmat,
                                                 float* __restrict__ alphap,      // [ET_*5] overflow scratch
                                                 float* __restrict__ invb,        // [NN*8] per-node 1/sum
                                                 const float* __restrict__ bias,
                                                 const float* __restrict__ lns, const float* __restrict__ lnb,
                                                 uint4* __restrict__ xpk) {       // packed-A output
    __shared__ float sExp[4][64 * 5];
    __shared__ int   sSrc[4][64];
    int wv   = threadIdx.x >> 6;
    int lane = threadIdx.x & 63;
    int node = blockIdx.x * 4 + wv;
    if (node >= NN) return;
    int start = rowptr[node], end = rowptr[node + 1];
    int deg = end - start;
    bool fits = (deg <= 64);
    float4 dd4 = *reinterpret_cast<const float4*>(&ald[(size_t)node * 8]);
    float  dd5 = ald[(size_t)node * 8 + 4];
    float ad[5] = {dd4.x, dd4.y, dd4.z, dd4.w, dd5};

    // ---- pass 1: exp(leaky(logit)), lane-parallel over edges ----
    float sm[5] = {0.f, 0.f, 0.f, 0.f, 0.f};
    for (int j = start + lane; j < end; j += 64) {
        int sy = esrc[j];
        int idx = j - start;
        if (fits) sSrc[wv][idx] = sy;
        const float* as = &als[(size_t)sy * 8];
        float4 a4 = *reinterpret_cast<const float4*>(as);
        float  a5 = as[4];
        float asv[5] = {a4.x, a4.y, a4.z, a4.w, a5};
#pragma unroll
        for (int h = 0; h < 5; h++) {
            float l = asv[h] + ad[h];
            l = l > 0.f ? l : 0.2f * l;
            float ex = __expf(fminf(l, 60.f));
            sm[h] += ex;
            if (fits) sExp[wv][idx * 5 + h] = ex;
            else      alphap[(size_t)j * 5 + h] = ex;
        }
    }
#pragma unroll
    for (int off = 32; off >= 1; off >>= 1)
#pragma unroll
        for (int h = 0; h < 5; h++) sm[h] += __shfl_xor(sm[h], off);
    float inv[5];
#pragma unroll
    for (int h = 0; h < 5; h++) inv[h] = 1.f / (sm[h] + 1e-16f);
    if (lane == 0) {
        float* ip = &invb[(size_t)node * 8];
        ip[0] = inv[0]; ip[1] = inv[1]; ip[2] = inv[2]; ip[3] = inv[3]; ip[4] = inv[4];
    }
    // pre-normalize LDS weights (same product as per-use multiply -> bit-identical)
    if (fits && lane < deg) {
#pragma unroll
        for (int h = 0; h < 5; h++) sExp[wv][lane * 5 + h] *= inv[h];
    }

    int h0 = lane >> 4;            // head of ch pair (2l,2l+1): 0..3
    bool lo16 = lane < 16;         // lanes 0..15 own head-4 pair {128+2l,128+2l+1}
    int c01 = 2 * lane;            // first ch pair
    int c2  = 128 + 2 * lane;      // second ch pair (lo16 only; 128..158)
    float2 A0 = make_float2(0.f, 0.f), A1 = make_float2(0.f, 0.f);
    float2 A2 = make_float2(0.f, 0.f), A3 = make_float2(0.f, 0.f);
    float2 H0 = make_float2(0.f, 0.f), H1 = make_float2(0.f, 0.f);
    float2 H2 = make_float2(0.f, 0.f), H3 = make_float2(0.f, 0.f);

    if (fits) {
        // ---- aggregation: 4-edge unrolled, ch pairs across lanes ----
        int idx = 0;
        for (; idx + 3 < deg; idx += 4) {
            int s0 = sSrc[wv][idx], s1 = sSrc[wv][idx + 1];
            int s2 = sSrc[wv][idx + 2], s3 = sSrc[wv][idx + 3];
            float w0 = sExp[wv][(idx + 0) * 5 + h0];
            float w1 = sExp[wv][(idx + 1) * 5 + h0];
            float w2 = sExp[wv][(idx + 2) * 5 + h0];
            float w3 = sExp[wv][(idx + 3) * 5 + h0];
            const unsigned short* r0 = (const unsigned short*)&hmat[(size_t)s0 * HID_];
            const unsigned short* r1 = (const unsigned short*)&hmat[(size_t)s1 * HID_];
            const unsigned short* r2 = (const unsigned short*)&hmat[(size_t)s2 * HID_];
            const unsigned short* r3 = (const unsigned short*)&hmat[(size_t)s3 * HID_];
            float2 f0 = bf2f2(*reinterpret_cast<const uint32_t*>(&r0[c01]));
            float2 f1 = bf2f2(*reinterpret_cast<const uint32_t*>(&r1[c01]));
            float2 f2 = bf2f2(*reinterpret_cast<const uint32_t*>(&r2[c01]));
            float2 f3 = bf2f2(*reinterpret_cast<const uint32_t*>(&r3[c01]));
            A0.x += w0 * f0.x; A0.y += w0 * f0.y;
            A1.x += w1 * f1.x; A1.y += w1 * f1.y;
            A2.x += w2 * f2.x; A2.y += w2 * f2.y;
            A3.x += w3 * f3.x; A3.y += w3 * f3.y;
            if (lo16) {
                float u0 = sExp[wv][(idx + 0) * 5 + 4];
                float u1 = sExp[wv][(idx + 1) * 5 + 4];
                float u2 = sExp[wv][(idx + 2) * 5 + 4];
                float u3 = sExp[wv][(idx + 3) * 5 + 4];
                float2 g0 = bf2f2(*reinterpret_cast<const uint32_t*>(&r0[c2]));
                float2 g1 = bf2f2(*reinterpret_cast<const uint32_t*>(&r1[c2]));
                float2 g2 = bf2f2(*reinterpret_cast<const uint32_t*>(&r2[c2]));
                float2 g3 = bf2f2(*reinterpret_cast<const uint32_t*>(&r3[c2]));
                H0.x += u0 * g0.x; H0.y += u0 * g0.y;
                H1.x += u1 * g1.x; H1.y += u1 * g1.y;
                H2.x += u2 * g2.x; H2.y += u2 * g2.y;
                H3.x += u3 * g3.x; H3.y += u3 * g3.y;
            }
        }
        for (; idx < deg; idx++) {
            int s0 = sSrc[wv][idx];
            float w0 = sExp[wv][idx * 5 + h0];
            const unsigned short* r0 = (const unsigned short*)&hmat[(size_t)s0 * HID_];
            float2 f0 = bf2f2(*reinterpret_cast<const uint32_t*>(&r0[c01]));
            A0.x += w0 * f0.x; A0.y += w0 * f0.y;
            if (lo16) {
                float u0 = sExp[wv][idx * 5 + 4];
                float2 g0 = bf2f2(*reinterpret_cast<const uint32_t*>(&r0[c2]));
                H0.x += u0 * g0.x; H0.y += u0 * g0.y;
            }
        }
    } else {
        // ---- overflow path (deg > 64): exp staged in global scratch ----
        for (int j = start; j < end; j++) {
            int s0 = esrc[j];
            float w0 = alphap[(size_t)j * 5 + h0] * inv[h0];
            const unsigned short* r0 = (const unsigned short*)&hmat[(size_t)s0 * HID_];
            float2 f0 = bf2f2(*reinterpret_cast<const uint32_t*>(&r0[c01]));
            A0.x += w0 * f0.x; A0.y += w0 * f0.y;
            if (lo16) {
                float u0 = alphap[(size_t)j * 5 + 4] * inv[4];
                float2 g0 = bf2f2(*reinterpret_cast<const uint32_t*>(&r0[c2]));
                H0.x += u0 * g0.x; H0.y += u0 * g0.y;
            }
        }
    }
    float2 A = make_float2(A0.x + A1.x + A2.x + A3.x, A0.y + A1.y + A2.y + A3.y);
    float2 Hh = make_float2(H0.x + H1.x + H2.x + H3.x, H0.y + H1.y + H2.y + H3.y);

    // ---- bias + leaky(0.01) + LayerNorm ----
    float2 bb = *reinterpret_cast<const float2*>(&bias[c01]);
    float v0 = A.x + bb.x;  v0 = v0 > 0.f ? v0 : 0.01f * v0;
    float v1 = A.y + bb.y;  v1 = v1 > 0.f ? v1 : 0.01f * v1;
    float v2 = 0.f, v3 = 0.f;
    if (lo16) {
        float2 b2 = *reinterpret_cast<const float2*>(&bias[c2]);
        v2 = Hh.x + b2.x; v2 = v2 > 0.f ? v2 : 0.01f * v2;
        v3 = Hh.y + b2.y; v3 = v3 > 0.f ? v3 : 0.01f * v3;
    }
    float s  = v0 + v1 + v2 + v3;
    float sq = v0 * v0 + v1 * v1 + v2 * v2 + v3 * v3;
#pragma unroll
    for (int off = 32; off >= 1; off >>= 1) {
        s  += __shfl_xor(s, off);
        sq += __shfl_xor(sq, off);
    }
    float m = s * (1.f / 160.f);
    float r = rsqrtf(sq * (1.f / 160.f) - m * m + 1e-5f);
    uint32_t pk1, pk2 = 0u;
    {
        float2 sc = *reinterpret_cast<const float2*>(&lns[c01]);
        float2 bi = *reinterpret_cast<const float2*>(&lnb[c01]);
        pk1 = (uint32_t)f2bf((v0 - m) * r * sc.x + bi.x)
            | ((uint32_t)f2bf((v1 - m) * r * sc.y + bi.y) << 16);
    }
    if (lo16) {
        float2 sc = *reinterpret_cast<const float2*>(&lns[c2]);
        float2 bi = *reinterpret_cast<const float2*>(&lnb[c2]);
        pk2 = (uint32_t)f2bf((v2 - m) * r * sc.x + bi.x)
            | ((uint32_t)f2bf((v3 - m) * r * sc.y + bi.y) << 16);
    }
    // ---- repack node row into GEMM fragment chunks (20 x 16B) ----
    // chunk j covers ch 8j..8j+7 = pairs 4j..4j+3 (pk1 of lanes 4j.. if j<16,
    // else pk2 of lanes 4(j-16)..). srcb clamped so every __shfl lane index is
    // in range for all 64 lanes (results discarded for j>=20).
    int j = lane;
    int srcb = (j < 16) ? (4 * j) : (4 * ((j - 16) & 15));
    uint32_t a0w = __shfl(pk1, srcb + 0), a1w = __shfl(pk1, srcb + 1);
    uint32_t a2w = __shfl(pk1, srcb + 2), a3w = __shfl(pk1, srcb + 3);
    uint32_t b0w = __shfl(pk2, srcb + 0), b1w = __shfl(pk2, srcb + 1);
    uint32_t b2w = __shfl(pk2, srcb + 2), b3w = __shfl(pk2, srcb + 3);
    if (j < 20) {
        uint4 val;
        val.x = (j < 16) ? a0w : b0w;
        val.y = (j < 16) ? a1w : b1w;
        val.z = (j < 16) ? a2w : b2w;
        val.w = (j < 16) ? a3w : b3w;
        int blk = node >> 6, wq = (node >> 4) & 3, fr = node & 15;
        int ks = j >> 2, q = j & 3;
        size_t cidx = (size_t)(blk * NK2 + ks) * 256 + wq * 64 + q * 16 + fr;
        xpk[cidx] = val;
    }
}

// ---------------- readout MLP (single block) ----------------
__global__ __launch_bounds__(256) void k_mlp(const float* __restrict__ pooled, const int* __restrict__ batch,
                                             const float* __restrict__ W1, const float* __restrict__ b1,
                                             const float* __restrict__ lns, const float* __restrict__ lnb,
                                             const float* __restrict__ W2, const float* __restrict__ b2,
                                             float* __restrict__ rec) {
    __shared__ float P[GG][HID_];
    __shared__ float Z[GG][HID_];
    __shared__ float mu[GG], rr[GG], ic[GG];
    int t = threadIdx.x;
    if (t < GG) {
        int lo = lbound_i(batch, NN, t), hi = lbound_i(batch, NN, t + 1);
        ic[t] = 1.f / fmaxf((float)(hi - lo), 1.f);
    }
    __syncthreads();
    for (int i = t; i < GG * HID_; i += 256) P[i / HID_][i % HID_] = pooled[i] * ic[i / HID_];
    __syncthreads();
    for (int i = t; i < GG * HID_; i += 256) {
        int g = i / HID_, j = i % HID_;
        float acc = b1[j];
        for (int k = 0; k < HID_; k++) acc += P[g][k] * W1[k * HID_ + j];
        Z[g][j] = acc;
    }
    __syncthreads();
    if (t < GG) {
        float s = 0.f, sq = 0.f;
        for (int k = 0; k < HID_; k++) { float z = Z[t][k]; s += z; sq += z * z; }
        float m = s / (float)HID_;
        mu[t] = m;
        rr[t] = rsqrtf(sq / (float)HID_ - m * m + 1e-5f);
    }
    __syncthreads();
    for (int i = t; i < GG * HID_; i += 256) {
        int g = i / HID_, j = i % HID_;
        float z = (Z[g][j] - mu[g]) * rr[g] * lns[j] + lnb[j];
        Z[g][j] = fmaxf(z, 0.f);
    }
    __syncthreads();
    for (int i = t; i < GG * NC_; i += 256) {
        int g = i / NC_, j = i % NC_;
        float acc = b2[j];
        for (int k = 0; k < HID_; k++) acc += Z[g][k] * W2[k * NC_ + j];
        rec[g * NC_ + j] = acc;
    }
}

extern "C" void kernel_launch(void* const* d_in, const int* in_sizes, int n_in,
                              void* d_out, int out_size, void* d_ws, size_t ws_size,
                              hipStream_t stream) {
    const float* x    = (const float*)d_in[0];
    const int*   ei   = (const int*)d_in[1];
    const int*   batch= (const int*)d_in[2];
    const float* W1   = (const float*)d_in[3];
    const float* as1  = (const float*)d_in[4];
    const float* ad1  = (const float*)d_in[5];
    const float* b1   = (const float*)d_in[6];
    const float* ln1s = (const float*)d_in[7];
    const float* ln1b = (const float*)d_in[8];
    const float* W2   = (const float*)d_in[9];
    const float* as2  = (const float*)d_in[10];
    const float* ad2  = (const float*)d_in[11];
    const float* b2   = (const float*)d_in[12];
    const float* ln2s = (const float*)d_in[13];
    const float* ln2b = (const float*)d_in[14];
    const float* Wm   = (const float*)d_in[15];
    const float* bm   = (const float*)d_in[16];
    const float* Wm1  = (const float*)d_in[17];
    const float* bm1  = (const float*)d_in[18];
    const float* ln3s = (const float*)d_in[19];
    const float* ln3b = (const float*)d_in[20];
    const float* Wm2  = (const float*)d_in[21];
    const float* bm2  = (const float*)d_in[22];

    float* out    = (float*)d_out;
    float* xo     = out;                              // N*160
    float* rec    = out + (size_t)NN * HID_;          // 8*20
    float* alpha1 = rec + GG * NC_;                   // ET*5
    float* alpha2 = alpha1 + (size_t)ET_ * 5;         // ET*5

    char* w = (char*)d_ws;
    auto carve = [&](size_t bytes) { char* p = w; w += (bytes + 255) & ~(size_t)255; return p; };
    int*   deg    = (int*)carve((size_t)NN * 4);
    int*   rowptr = (int*)carve((size_t)(NN + 1) * 4);
    int*   cursor = (int*)carve((size_t)NN * 4);
    int*   esrc   = (int*)carve((size_t)ET_ * 4);
    int*   bsum   = (int*)carve(64 * 4);
    __hip_bfloat16* hbuf = (__hip_bfloat16*)carve((size_t)NN * HID_ * 2);
    uint4* xpk    = (uint4*)carve((size_t)GB1 * NK2 * 256 * 16);  // packed attn output (16MB)
    float* alphap = (float*)carve((size_t)ET_ * 5 * 4);
    float* als1   = (float*)carve((size_t)NN * 8 * 4);   // ping-pong dot buffers:
    float* ald1   = (float*)carve((size_t)NN * 8 * 4);   // layer-1 dots live while the
    float* als2   = (float*)carve((size_t)NN * 8 * 4);   // fused gemm2 writes layer-2
    float* ald2   = (float*)carve((size_t)NN * 8 * 4);   // dots (no race)
    float* invb   = (float*)carve((size_t)NN * 8 * 4);
    float* pooled = (float*)carve((size_t)GG * HID_ * 4);
    ab8*   B1pk   = (ab8*)carve((size_t)NK1 * 10 * 64 * 16);     // 160 KB
    ab8*   B2pk   = (ab8*)carve((size_t)NK2 * 10 * 64 * 16);     // 50 KB
    ab8*   Bmpk   = (ab8*)carve((size_t)NK2 * 10 * 64 * 16);     // 50 KB
    // Apk (51.25MB) lives in d_out: dead after the layer-1 GEMM; alpha1/xo writes
    // to that region all happen in later dispatches.
    ab8*   Apk    = (ab8*)d_out;                                 // GB1*NK1*256*16 B

    // ---- 1. prep: zero deg/pooled + pack all B weights ----
    k_prep0<<<(NN + 255) / 256, 256, 0, stream>>>(W1, B1pk, W2, B2pk, Wm, Bmpk, pooled, deg);

    // ---- 2. fused streaming conv + hist ----
    k_hist_conv<<<GB1 + EBH, 256, 0, stream>>>(ei, deg, x, Apk);

    // ---- 3-5. CSR scans ----
    int nb = (NN + 1023) / 1024;
    k_scan1<<<nb, 256, 0, stream>>>(deg, rowptr, bsum);
    k_scan2<<<1, 64, 0, stream>>>(bsum, nb);
    k_scan3<<<(NN + 1 + 255) / 256, 256, 0, stream>>>(rowptr, bsum, cursor);

    const int NWB = (NN + 3) / 4;         // wave-per-node blocks (4 waves/block)

    // ---- 6. fused: layer-1 GEMM + CSR scatter ----
    k_gemm_scatter<<<GB1 + EBH, 256, 0, stream>>>(Apk, B1pk, NK1, nullptr, hbuf, NN, nullptr, 0,
                                                  as1, ad1, als1, ald1, nullptr, nullptr,
                                                  ei, cursor, esrc);

    // ---- 7. layer-1 attention ----
    k_att_agg<<<NWB, 256, 0, stream>>>(rowptr, esrc, als1, ald1, hbuf, alphap, invb,
                                       b1, ln1s, ln1b, xpk);

    // ---- 8. fused: layer-2 GEMM + alpha1 emission ----
    k_gemm_alpha<<<GB1 + EBH, 256, 0, stream>>>((const ab8*)xpk, B2pk, NK2, nullptr, hbuf, NN,
                                                nullptr, 0, as2, ad2, als2, ald2, nullptr, nullptr,
                                                ei, als1, ald1, invb, alpha1);

    // ---- 9. layer-2 attention ----
    k_att_agg<<<NWB, 256, 0, stream>>>(rowptr, esrc, als2, ald2, hbuf, alphap, invb,
                                       b2, ln2s, ln2b, xpk);

    // ---- 10. fused: readout GEMM (+mean-pool partials) + alpha2 emission ----
    k_gemm_alpha<<<GB1 + EBH, 256, 0, stream>>>((const ab8*)xpk, Bmpk, NK2, xo, nullptr, NN,
                                                bm, 1, nullptr, nullptr, nullptr, nullptr, batch, pooled,
                                                ei, als2, ald2, invb, alpha2);

    // ---- 11. readout MLP ----
    k_mlp<<<1, 256, 0, stream>>>(pooled, batch, Wm1, bm1, ln3s, ln3b, Wm2, bm2, rec);
}